// Round 5
// baseline (683.837 us; speedup 1.0000x reference)
//
#include <hip/hip_runtime.h>
#include <cstdint>

#define N_NODES 100000
#define N_EDGES 500000
#define N_GRAPHS 128
#define HID 128
#define SCAN1_B ((2 * N_NODES + 255) / 256)   // 782 blocks over concatenated counts
#define N_SEG (N_EDGES / 16)                  // 31250 16-edge segments per layer (phase-3 quarter granularity)
#define EDGE_GRID 512                         // persistent edge blocks: 2/CU x 256 CU

typedef __attribute__((ext_vector_type(8))) short short8;
typedef __attribute__((ext_vector_type(4))) float f32x4;

// ---- raw workgroup barrier: drains LDS only, leaves VMEM in flight.
//      (__syncthreads() emits s_waitcnt vmcnt(0) before s_barrier, which
//      force-drains the cross-window prefetch and serializes gather latency
//      into every window — the R0-R4 invariant bottleneck.) ----
__device__ __forceinline__ void wg_barrier() {
    asm volatile("s_waitcnt lgkmcnt(0)\n\ts_barrier" ::: "memory");
}

// ---- monotone float<->uint encoding for max; enc==0 marks "never written" ----
__device__ __forceinline__ unsigned encf(float f) {
    unsigned u = __float_as_uint(f);
    return (u & 0x80000000u) ? ~u : (u | 0x80000000u);
}
__device__ __forceinline__ float decf(unsigned e) {
    unsigned u = (e & 0x80000000u) ? (e & 0x7FFFFFFFu) : ~e;
    return __uint_as_float(u);
}
__device__ __forceinline__ unsigned pk_bf16(float a, float b) {
    unsigned ua = __float_as_uint(a);
    unsigned ub = __float_as_uint(b);
    ua = (ua + 0x7fffu + ((ua >> 16) & 1u)) >> 16;
    ub = (ub + 0x7fffu + ((ub >> 16) & 1u)) & 0xffff0000u;
    return ua | ub;
}
__device__ __forceinline__ ushort bf16r(float f) {
    unsigned u = __float_as_uint(f);
    return (ushort)((u + 0x7fffu + ((u >> 16) & 1u)) >> 16);
}
__device__ __forceinline__ float bf2f(ushort h) {
    return __uint_as_float((unsigned)h << 16);
}

// ---- transpose+convert weights -> bf16 [n][k], D computed on the fly;
//      block 384 does the prep (wkey/bias0); blocks >=385 zero cnt + pooled ----
__global__ __launch_bounds__(256) void transp_prep_kernel(const float* __restrict__ W1b,
                                                          const float* __restrict__ W2b,
                                                          const float* __restrict__ W1a,
                                                          const float* __restrict__ W2a,
                                                          const float* __restrict__ W_enc,
                                                          const float* __restrict__ b_enc,
                                                          const float* __restrict__ W0,
                                                          const float* __restrict__ b0,
                                                          ushort* __restrict__ WT,
                                                          float* __restrict__ wkey,
                                                          float* __restrict__ bias0,
                                                          int* __restrict__ cnt,
                                                          float* __restrict__ pooled) {
    int blk = blockIdx.x;
    int tid = threadIdx.x;
    if (blk >= 385) {   // zeroing duty: 782 blocks for cnt, 256 for pooled
        int z = blk - 385;
        if (z < SCAN1_B) {
            int i = z * 256 + tid;
            if (i < 2 * N_NODES) cnt[i] = 0;
        } else {
            int i = (z - SCAN1_B) * 256 + tid;   // exactly 128*512 = 65536 floats
            pooled[i] = 0.f;
        }
        return;
    }
    if (blk == 384) {   // prep
        if (tid < HID) {
            float wk = 0.f, bk = b0[tid];
            for (int k = 0; k < 32; ++k) {
                float w = W0[(15 + k) * HID + tid];
                wk += W_enc[k] * w;
                bk += b_enc[k] * w;
            }
            wkey[tid] = wk;
            bias0[tid] = bk;
        }
        return;
    }
    int m = blk >> 6;
    int i = (blk & 63) * 256 + tid;   // i = n*128 + k
    int n = i >> 7, k = i & 127;
    int src = k * HID + n;
    float v;
    switch (m) {
        case 0: v = W1b[src]; break;
        case 1: v = W2b[src]; break;
        case 2: v = W1a[src]; break;
        case 3: v = W1a[HID * HID + src] - W1a[src]; break;
        case 4: v = W2a[src]; break;
        default: v = W2a[HID * HID + src] - W2a[src]; break;
    }
    WT[m * HID * HID + i] = bf16r(v);
}

// ---- encoder: h = relu(features @ W0[0:15] + key*wkey + bias0) -> bf16;
//      also emits dense xkey[n] = x[n*16] for the edge kernels ----
__global__ __launch_bounds__(256) void encode_kernel(const float* __restrict__ x,
                                                     const float* __restrict__ W0,
                                                     const float* __restrict__ wkey,
                                                     const float* __restrict__ bias0,
                                                     ushort* __restrict__ h,
                                                     float* __restrict__ xkey) {
    int n = blockIdx.x * 2 + (threadIdx.x >> 7);
    int j = threadIdx.x & 127;
    const float* xr = x + n * 16;
    float k0 = xr[0];
    if (j == 0) xkey[n] = k0;
    float acc = bias0[j] + k0 * wkey[j];
#pragma unroll
    for (int f = 0; f < 15; ++f)
        acc = fmaf(xr[1 + f], W0[f * HID + j], acc);
    h[n * HID + j] = bf16r(fmaxf(acc, 0.f));
}

// ---- dual MFMA (N x 128 bf16) @ (128 x 128) -> bf16, LDS-restaged epilogue ----
__global__ __launch_bounds__(256, 4) void mm_mfma_dual_kernel(const ushort* __restrict__ in,
                                                              const unsigned* __restrict__ aggin,
                                                              const int* __restrict__ cntin,
                                                              const float* __restrict__ baddin,
                                                              ushort* __restrict__ xout,
                                                              const ushort* __restrict__ WuT,
                                                              const ushort* __restrict__ WvT,
                                                              const float* __restrict__ bv,
                                                              ushort* __restrict__ outu,
                                                              ushort* __restrict__ outv, int nrows) {
    __shared__ ushort sH[128 * 136];   // A-tile, then reused for D-restage
    int tid = threadIdx.x;
    int n0 = blockIdx.x * 128;
#pragma unroll
    for (int q = 0; q < 8; ++q) {
        int c = q * 256 + tid;
        int r = c >> 4, off = (c & 15) << 3;
        int n = n0 + r;
        uint4 vv = make_uint4(0, 0, 0, 0);
        if (n < nrows) {
            uint4 hv = *(const uint4*)(in + (size_t)n * HID + off);
            if (aggin) {
                float add[8];
#pragma unroll
                for (int p = 0; p < 8; ++p) add[p] = 0.f;
                if (cntin[n] > 0) {
                    uint4 e0 = *(const uint4*)(aggin + (size_t)n * HID + off);
                    uint4 e1 = *(const uint4*)(aggin + (size_t)n * HID + off + 4);
                    float4 bb0 = *(const float4*)(baddin + off);
                    float4 bb1 = *(const float4*)(baddin + off + 4);
                    add[0] = decf(e0.x) + bb0.x; add[1] = decf(e0.y) + bb0.y;
                    add[2] = decf(e0.z) + bb0.z; add[3] = decf(e0.w) + bb0.w;
                    add[4] = decf(e1.x) + bb1.x; add[5] = decf(e1.y) + bb1.y;
                    add[6] = decf(e1.z) + bb1.z; add[7] = decf(e1.w) + bb1.w;
                }
                unsigned hw[4] = {hv.x, hv.y, hv.z, hv.w};
                unsigned ow[4];
#pragma unroll
                for (int p = 0; p < 4; ++p) {
                    float lo = __uint_as_float(hw[p] << 16);
                    float hi = __uint_as_float(hw[p] & 0xffff0000u);
                    float r0 = fmaxf(add[2 * p] + lo, 0.f);
                    float r1 = fmaxf(add[2 * p + 1] + hi, 0.f);
                    ow[p] = pk_bf16(r0, r1);
                }
                vv = make_uint4(ow[0], ow[1], ow[2], ow[3]);
                *(uint4*)(xout + (size_t)n * HID + off) = vv;
            } else {
                vv = hv;
            }
        }
        *(uint4*)(sH + r * 136 + off) = vv;
    }
    __syncthreads();

    int lane = tid & 63, wv = tid >> 6;
    int l15 = lane & 15, quad = lane >> 4;

    short8 afr[2][4];
#pragma unroll
    for (int rr = 0; rr < 2; ++rr) {
        const ushort* ab = sH + (wv * 32 + rr * 16 + l15) * 136 + quad * 8;
#pragma unroll
        for (int kc = 0; kc < 4; ++kc)
            afr[rr][kc] = *(const short8*)(ab + kc * 32);
    }

#pragma unroll
    for (int pass = 0; pass < 2; ++pass) {
        const ushort* WT = pass ? WvT : WuT;
        ushort* out = pass ? outv : outu;
        f32x4 acc[2][8];
#pragma unroll
        for (int rr = 0; rr < 2; ++rr)
#pragma unroll
            for (int ct = 0; ct < 8; ++ct) acc[rr][ct] = (f32x4){0.f, 0.f, 0.f, 0.f};
#pragma unroll
        for (int kc = 0; kc < 4; ++kc) {
#pragma unroll
            for (int ct = 0; ct < 8; ++ct) {
                short8 bfr = *(const short8*)(WT + (ct * 16 + l15) * 128 + quad * 8 + kc * 32);
                acc[0][ct] = __builtin_amdgcn_mfma_f32_16x16x32_bf16(afr[0][kc], bfr, acc[0][ct], 0, 0, 0);
                acc[1][ct] = __builtin_amdgcn_mfma_f32_16x16x32_bf16(afr[1][kc], bfr, acc[1][ct], 0, 0, 0);
            }
        }
        __syncthreads();
#pragma unroll
        for (int ct = 0; ct < 8; ++ct) {
            int col = ct * 16 + l15;
            float bb = pass ? bv[col] : 0.f;
#pragma unroll
            for (int rr = 0; rr < 2; ++rr) {
                int rowb = wv * 32 + rr * 16 + quad * 4;
#pragma unroll
                for (int reg = 0; reg < 4; ++reg)
                    sH[(rowb + reg) * 136 + col] = bf16r(acc[rr][ct][reg] + bb);
            }
        }
        __syncthreads();
#pragma unroll
        for (int q = 0; q < 8; ++q) {
            int c = q * 256 + tid;
            int r = c >> 4, off = (c & 15) << 3;
            int m = n0 + r;
            if (m < nrows)
                *(uint4*)(out + (size_t)m * HID + off) = *(const uint4*)(sH + r * 136 + off);
        }
    }
}

// ---- merged CSR build for BOTH layers ----
__global__ __launch_bounds__(256) void hist_kernel(const int* __restrict__ dst1,
                                                   const int* __restrict__ dst2,
                                                   int* __restrict__ cnt) {
    int e = blockIdx.x * 256 + threadIdx.x;
    if (e < N_EDGES) atomicAdd(&cnt[dst1[e]], 1);
    else if (e < 2 * N_EDGES) atomicAdd(&cnt[N_NODES + dst2[e - N_EDGES]], 1);
}

__global__ __launch_bounds__(256) void scan1_kernel(const int* __restrict__ cnt,
                                                    int* __restrict__ cursor,
                                                    int* __restrict__ partials) {
    __shared__ int tmp[256];
    int tid = threadIdx.x;
    int gid = blockIdx.x * 256 + tid;
    int v = (gid < 2 * N_NODES) ? cnt[gid] : 0;
    tmp[tid] = v;
    __syncthreads();
#pragma unroll
    for (int off = 1; off < 256; off <<= 1) {
        int t = (tid >= off) ? tmp[tid - off] : 0;
        __syncthreads();
        tmp[tid] += t;
        __syncthreads();
    }
    if (gid < 2 * N_NODES) cursor[gid] = tmp[tid] - v;   // local exclusive
    if (tid == 255) partials[blockIdx.x] = tmp[255];
}

__global__ __launch_bounds__(1024) void scan2_kernel(int* __restrict__ partials) {
    __shared__ int tmp[1024];
    int tid = threadIdx.x;
    int v = (tid < SCAN1_B) ? partials[tid] : 0;
    tmp[tid] = v;
    __syncthreads();
#pragma unroll
    for (int off = 1; off < 1024; off <<= 1) {
        int t = (tid >= off) ? tmp[tid - off] : 0;
        __syncthreads();
        tmp[tid] += t;
        __syncthreads();
    }
    if (tid < SCAN1_B) partials[tid] = tmp[tid] - v;  // exclusive
}

__global__ __launch_bounds__(256) void scatter_kernel(const int* __restrict__ src1,
                                                      const int* __restrict__ dst1,
                                                      const int* __restrict__ src2,
                                                      const int* __restrict__ dst2,
                                                      int* __restrict__ cursor,
                                                      const int* __restrict__ partials,
                                                      int2* __restrict__ pedge) {
    int e = blockIdx.x * 256 + threadIdx.x;
    if (e < N_EDGES) {
        int d = dst1[e];
        int pos = atomicAdd(&cursor[d], 1) + partials[d >> 8];
        pedge[pos] = make_int2(src1[e], d);
    } else if (e < 2 * N_EDGES) {
        int d = dst2[e - N_EDGES];
        int idx = N_NODES + d;
        int pos = atomicAdd(&cursor[idx], 1) + partials[idx >> 8];
        pedge[pos] = make_int2(src2[e - N_EDGES], d);   // pos lands in [N_EDGES, 2*N_EDGES)
    }
}

// ---- zero boundary agg rows for BOTH layers in one launch (u32 arrays).
//      16-edge granularity to match the phase-3 quarter size at window=64 ----
__global__ __launch_bounds__(256) void zbound_both_kernel(const int2* __restrict__ pedge,
                                                          unsigned* __restrict__ agg1,
                                                          unsigned* __restrict__ agg2) {
    int b = blockIdx.x * 4 + (threadIdx.x >> 6);
    int lane = threadIdx.x & 63;
    if (b >= 2 * N_SEG) return;
    int layer = b >= N_SEG;
    int bl = b - layer * N_SEG;
    const int2* pe = pedge + (size_t)layer * N_EDGES;
    unsigned* agg = layer ? agg2 : agg1;
    int d;
    if (bl == 0) {
        d = pe[N_EDGES - 1].y;               // tail row (clamped duplicates -> atomics)
    } else {
        int da = pe[bl * 16 - 1].y, db = pe[bl * 16].y;
        if (da != db) return;
        d = db;
    }
    *(uint2*)(agg + (size_t)d * HID + lane * 2) = make_uint2(0u, 0u);
}

// ---- edge conv: bf16 MFMA, 64-edge dst-sorted windows, 512 threads ----
// v6 (persistent + pipelined + RAW BARRIERS): __syncthreads() drains
// vmcnt(0), force-completing the cross-window prefetch at the first barrier
// of every window -- that drain was the R0-R5 invariant bottleneck. wg_barrier()
// (lgkmcnt(0)+s_barrier only) keeps the next-window gather in flight across
// the whole window; the backend waits with counted vmcnt at actual use.
__global__ __launch_bounds__(512, 4) void edge_kernel(const ushort* __restrict__ u,
                                                      const ushort* __restrict__ v,
                                                      const float* __restrict__ xkey,
                                                      const int2* __restrict__ pedge,
                                                      const ushort* __restrict__ WbT,
                                                      const float* __restrict__ wlast,
                                                      unsigned* __restrict__ agg) {
    __shared__ ushort sWT[128 * 136];   // 34816 B: WbT[n][k] bf16, padded stride
    __shared__ ushort sU[64 * 136];     // 17408 B union: t[64][136] then msgT[128][66]
    __shared__ int sDst[64];
    __shared__ int sBnd[2];             // [0]=dst before window, [1]=dst after window
    int tid = threadIdx.x;
    const int nwin = (N_EDGES + 63) >> 6;   // 7813
    const int gstep = EDGE_GRID;

    // W stage once per block: 2048 uint4 over 512 threads = 4 each (L2-hot 32KB)
#pragma unroll
    for (int q = 0; q < 4; ++q) {
        int c = q * 512 + tid;
        int n = c >> 4, off = (c & 15) << 3;
        *(uint4*)(sWT + n * 136 + off) = *(const uint4*)(WbT + n * 128 + off);
    }

    int eloc = tid >> 3;
    int sub = tid & 7;
    int kb = sub << 4;
    int lane = tid & 63, wv = tid >> 6;
    int l15 = lane & 15, quad = lane >> 4;
    int ch = wv & 1, rh = wv >> 1;

    // loop-invariant wlast slice for this thread's 16 columns -> registers
    float wreg[16];
    {
        const float4* wr4 = (const float4*)(wlast + kb);
#pragma unroll
        for (int q = 0; q < 4; ++q) {
            float4 wq = wr4[q];
            wreg[q * 4 + 0] = wq.x; wreg[q * 4 + 1] = wq.y;
            wreg[q * 4 + 2] = wq.z; wreg[q * 4 + 3] = wq.w;
        }
    }

    int w = blockIdx.x;

    // prologue: meta+data for window w; meta for w+gstep
    int e0 = w * 64 + eloc; if (e0 >= N_EDGES) e0 = N_EDGES - 1;
    int2 sd_c = pedge[e0];
    float kxs_c = xkey[sd_c.x], kxd_c = xkey[sd_c.y];
    uint4 uu_c0, uu_c1, vv_c0, vv_c1;
    {
        const uint4* ur = (const uint4*)(u + (size_t)sd_c.x * HID + kb);
        const uint4* vr = (const uint4*)(v + (size_t)sd_c.y * HID + kb);
        uu_c0 = ur[0]; uu_c1 = ur[1];
        vv_c0 = vr[0]; vv_c1 = vr[1];
    }
    int e1 = (w + gstep) * 64 + eloc; if (e1 >= N_EDGES) e1 = N_EDGES - 1;
    int2 sd_n = pedge[e1];

    for (; w < nwin; w += gstep) {
        int w0 = w * 64;

        // ---- prefetch region: issue NEXT window's gathers + this window's
        //      boundary meta; sched_barrier pins these above the compute ----
        if (tid < 2) {
            int eb = (tid == 0) ? (w0 - 1) : (w0 + 64);
            int dv = (eb >= 0 && eb < N_EDGES) ? pedge[eb].y : -1;
            sBnd[tid] = dv;
        }
        float kxs_n = xkey[sd_n.x];
        float kxd_n = xkey[sd_n.y];
        uint4 uu_n0, uu_n1, vv_n0, vv_n1;
        {
            const uint4* ur = (const uint4*)(u + (size_t)sd_n.x * HID + kb);
            const uint4* vr = (const uint4*)(v + (size_t)sd_n.y * HID + kb);
            uu_n0 = ur[0]; uu_n1 = ur[1];
            vv_n0 = vr[0]; vv_n1 = vr[1];
        }
        int e2 = (w + 2 * gstep) * 64 + eloc; if (e2 >= N_EDGES) e2 = N_EDGES - 1;
        int2 sd_nn = pedge[e2];
        __builtin_amdgcn_sched_barrier(0);   // loads above may not sink below

        // phase 1: compute t for current window from registers
        {
            if (sub == 0) sDst[eloc] = sd_c.y;
            float kd = kxs_c - kxd_c;
            uint4 uu[2] = {uu_c0, uu_c1}, vv[2] = {vv_c0, vv_c1};
#pragma unroll
            for (int q = 0; q < 2; ++q) {
                unsigned pu[4] = {uu[q].x, uu[q].y, uu[q].z, uu[q].w};
                unsigned pv[4] = {vv[q].x, vv[q].y, vv[q].z, vv[q].w};
                unsigned pk[4];
#pragma unroll
                for (int p = 0; p < 4; ++p) {
                    float a0 = __uint_as_float(pu[p] << 16) + __uint_as_float(pv[p] << 16);
                    float a1 = __uint_as_float(pu[p] & 0xffff0000u) + __uint_as_float(pv[p] & 0xffff0000u);
                    a0 = fmaf(kd, wreg[q * 8 + 2 * p], a0);
                    a1 = fmaf(kd, wreg[q * 8 + 2 * p + 1], a1);
                    a0 = a0 > 0.f ? a0 : 0.1f * a0;
                    a1 = a1 > 0.f ? a1 : 0.1f * a1;
                    pk[p] = pk_bf16(a0, a1);
                }
                uint4 o; o.x = pk[0]; o.y = pk[1]; o.z = pk[2]; o.w = pk[3];
                *(uint4*)(sU + eloc * 136 + kb + q * 8) = o;
            }
        }
        wg_barrier();   // t + sDst + sBnd ready (first iter: also covers W-stage)

        // phase 2: MFMA. wave wv: rows (wv>>1)*16..+15, cols (wv&1)*64..+63
        short8 afr[4];
        {
            const ushort* ab = sU + (rh * 16 + l15) * 136 + quad * 8;
#pragma unroll
            for (int kc = 0; kc < 4; ++kc)
                afr[kc] = *(const short8*)(ab + kc * 32);
        }
        f32x4 acc[4];
#pragma unroll
        for (int ct = 0; ct < 4; ++ct) acc[ct] = (f32x4){0.f, 0.f, 0.f, 0.f};
#pragma unroll
        for (int kc = 0; kc < 4; ++kc) {
#pragma unroll
            for (int ct = 0; ct < 4; ++ct) {
                short8 bfr = *(const short8*)(sWT + ((ch * 4 + ct) * 16 + l15) * 136 + quad * 8 + kc * 32);
                acc[ct] = __builtin_amdgcn_mfma_f32_16x16x32_bf16(afr[kc], bfr, acc[ct], 0, 0, 0);
            }
        }
        wg_barrier();   // all t reads done -> sU reusable

        // epilogue: msgT[col][edge] bf16, stride 66 (odd dword stride -> conflict-free)
#pragma unroll
        for (int ct = 0; ct < 4; ++ct) {
            int col = (ch * 4 + ct) * 16 + l15;
            uint2 pr;
            pr.x = pk_bf16(acc[ct][0], acc[ct][1]);
            pr.y = pk_bf16(acc[ct][2], acc[ct][3]);
            *(uint2*)(sU + col * 66 + rh * 16 + quad * 4) = pr;
        }
        wg_barrier();

        // phase 3: segmented max, 4 threads/col (quarter-window = 16 edges each)
        {
            int j = tid & 127;
            int q4 = tid >> 7;            // 0..3
            int eBeg = q4 * 16;
            const ushort* mrow = sU + j * 66 + eBeg;
            float vals[16];
#pragma unroll
            for (int q = 0; q < 4; ++q) {
                ushort4 mv = *(const ushort4*)(mrow + q * 4);
                vals[q * 4 + 0] = bf2f(mv.x);
                vals[q * 4 + 1] = bf2f(mv.y);
                vals[q * 4 + 2] = bf2f(mv.z);
                vals[q * 4 + 3] = bf2f(mv.w);
            }
            int prevD = (q4 == 0) ? sBnd[0] : sDst[eBeg - 1];
            int nextD = (q4 == 3) ? sBnd[1] : sDst[eBeg + 16];
            int cur = sDst[eBeg], rs = eBeg;
            float mx = vals[0];
            for (int e3 = 1; e3 < 16; ++e3) {
                int d = sDst[eBeg + e3];      // uniform across the quarter's lanes
                float vv2 = vals[e3];
                if (d != cur) {
                    unsigned en = encf(mx);
                    unsigned* ap = agg + (size_t)cur * HID + j;
                    if (rs == eBeg && cur == prevD) atomicMax(ap, en);
                    else *ap = en;
                    cur = d; rs = eBeg + e3; mx = vv2;
                } else {
                    mx = fmaxf(mx, vv2);
                }
            }
            unsigned en = encf(mx);
            unsigned* ap = agg + (size_t)cur * HID + j;
            if ((rs == eBeg && cur == prevD) || cur == nextD) atomicMax(ap, en);
            else *ap = en;
        }
        wg_barrier();   // phase-3 sU/sDst/sBnd reads done -> next iter may overwrite

        // rotate pipeline registers
        sd_c = sd_n; sd_n = sd_nn;
        kxs_c = kxs_n; kxd_c = kxd_n;
        uu_c0 = uu_n0; uu_c1 = uu_n1; vv_c0 = vv_n0; vv_c1 = vv_n1;
    }
}

// ---- pooling with fused layer-2 combine: x2 never materialized ----
__global__ __launch_bounds__(256) void pool_kernel(const ushort* __restrict__ x1,
                                                   const unsigned* __restrict__ agg2,
                                                   const float* __restrict__ b2b,
                                                   const int* __restrict__ cnt2,
                                                   const int* __restrict__ batch,
                                                   float* __restrict__ pooled) {
    int g = blockIdx.x >> 3, s = blockIdx.x & 7;
    int tid = threadIdx.x;
    int lo = 0, hi = N_NODES;
    while (lo < hi) { int mid = (lo + hi) >> 1; if (batch[mid] < g) lo = mid + 1; else hi = mid; }
    int start = lo;
    hi = N_NODES;
    while (lo < hi) { int mid = (lo + hi) >> 1; if (batch[mid] < g + 1) lo = mid + 1; else hi = mid; }
    int end = lo;
    int cnt = end - start;
    int b0 = start + (int)((long long)cnt * s / 8);
    int b1 = start + (int)((long long)cnt * (s + 1) / 8);
    if (b1 <= b0) return;
    int j = tid & 127;
    bool isx2 = tid >= 128;
    float bbj = isx2 ? b2b[j] : 0.f;
    float mx = -INFINITY, sm = 0.f;
    for (int n = b0; n < b1; ++n) {
        float xv = bf2f(x1[(size_t)n * HID + j]);
        float vv;
        if (isx2) {
            float a = 0.f;
            if (cnt2[n] > 0) a = decf(agg2[(size_t)n * HID + j]) + bbj;
            vv = fmaxf(a + xv, 0.f);
        } else {
            vv = xv;
        }
        mx = fmaxf(mx, vv);
        sm += vv;
    }
    atomicMax((unsigned*)pooled + (size_t)g * 512 + tid, encf(mx));
    atomicAdd(pooled + (size_t)g * 512 + 256 + tid, sm);
}

// ---- final MLP + log_softmax ----
__global__ __launch_bounds__(128) void final_kernel(const float* __restrict__ pooled,
                                                    const int* __restrict__ batch,
                                                    const float* __restrict__ Wf1,
                                                    const float* __restrict__ bf1,
                                                    const float* __restrict__ Wf2,
                                                    const float* __restrict__ bf2,
                                                    float* __restrict__ out) {
    __shared__ float sP[512];
    __shared__ float sH[128];
    int g = blockIdx.x, tid = threadIdx.x;
    int lo = 0, hi = N_NODES;
    while (lo < hi) { int mid = (lo + hi) >> 1; if (batch[mid] < g) lo = mid + 1; else hi = mid; }
    int start = lo;
    hi = N_NODES;
    while (lo < hi) { int mid = (lo + hi) >> 1; if (batch[mid] < g + 1) lo = mid + 1; else hi = mid; }
    int cnt = lo - start;
    float inv = 1.f / (float)(cnt > 1 ? cnt : 1);
#pragma unroll
    for (int q = 0; q < 4; ++q) {
        int idx = q * 128 + tid;
        float raw;
        if (idx < 256) {
            unsigned e = ((const unsigned*)pooled)[(size_t)g * 512 + idx];
            raw = (e == 0u) ? 0.f : decf(e);
        } else {
            raw = pooled[(size_t)g * 512 + idx] * inv;
        }
        sP[idx] = raw;
    }
    __syncthreads();
    float acc = bf1[tid];
    for (int k = 0; k < 512; ++k) acc = fmaf(sP[k], Wf1[k * HID + tid], acc);
    sH[tid] = fmaxf(acc, 0.f);
    __syncthreads();
    if (tid < 2) {
        float l = bf2[tid];
        for (int k = 0; k < 128; ++k) l = fmaf(sH[k], Wf2[k * 2 + tid], l);
        sP[tid] = l;
    }
    __syncthreads();
    if (tid == 0) {
        float l0 = sP[0], l1 = sP[1];
        float m = fmaxf(l0, l1);
        float ls = m + logf(expf(l0 - m) + expf(l1 - m));
        out[g * 2 + 0] = l0 - ls;
        out[g * 2 + 1] = l1 - ls;
    }
}

extern "C" void kernel_launch(void* const* d_in, const int* in_sizes, int n_in,
                              void* d_out, int out_size, void* d_ws, size_t ws_size,
                              hipStream_t stream) {
    const float* x     = (const float*)d_in[0];
    const float* W_enc = (const float*)d_in[1];
    const float* b_enc = (const float*)d_in[2];
    const float* W0    = (const float*)d_in[3];
    const float* b0    = (const float*)d_in[4];
    const float* W1a   = (const float*)d_in[5];
    const float* b1a   = (const float*)d_in[6];
    const float* W1b   = (const float*)d_in[7];
    const float* b1b   = (const float*)d_in[8];
    const float* W2a   = (const float*)d_in[9];
    const float* b2a   = (const float*)d_in[10];
    const float* W2b   = (const float*)d_in[11];
    const float* b2b   = (const float*)d_in[12];
    const float* Wf1   = (const float*)d_in[13];
    const float* bf1   = (const float*)d_in[14];
    const float* Wf2   = (const float*)d_in[15];
    const float* bf2   = (const float*)d_in[16];
    const int* src1    = (const int*)d_in[17];
    const int* dst1    = (const int*)d_in[18];
    const int* src2    = (const int*)d_in[19];
    const int* dst2    = (const int*)d_in[20];
    const int* batch   = (const int*)d_in[21];

    const size_t NB = (size_t)N_NODES * HID;     // 12.8M elements
    ushort* hbuf  = (ushort*)d_ws;               // h -> x1 (in place, bf16)
    unsigned* agg1 = (unsigned*)(hbuf + NB);     // layer-1 segment-max (u32 encoded)
    unsigned* agg2 = agg1 + NB;                  // layer-2 segment-max
    ushort* ubuf  = (ushort*)(agg2 + NB);        // u bf16
    ushort* vbuf  = ubuf + NB;                   // v bf16
    ushort* WT    = vbuf + NB;                   // 6 x 16384 bf16: Wb1,Wb2,Wu1,Wv1,Wu2,Wv2
    ushort* WbT1 = WT;
    ushort* WbT2 = WT + 1 * HID * HID;
    ushort* WuT1 = WT + 2 * HID * HID;
    ushort* WvT1 = WT + 3 * HID * HID;
    ushort* WuT2 = WT + 4 * HID * HID;
    ushort* WvT2 = WT + 5 * HID * HID;
    float* wkey  = (float*)(WT + 6 * HID * HID);
    float* bias0 = wkey + 128;
    float* xkey  = bias0 + 128;                  // dense per-node key (N_NODES fp32)
    float* pooled = xkey + N_NODES;              // 128*512 fp32
    int* cnt    = (int*)(pooled + 128 * 512);    // 2*N_NODES (both layers)
    int* cursor = cnt + 2 * N_NODES;             // 2*N_NODES
    int* partials = cursor + 2 * N_NODES;        // 1024
    int2* pedge = (int2*)(partials + 1024);      // 2*N_EDGES pairs (both layers)

    const int bothGrid = (2 * N_EDGES + 255) / 256;   // 3907
    const int mmGrid   = (N_NODES + 127) / 128;       // 782
    const int zbGrid   = (2 * N_SEG + 3) / 4;         // 15626 (both layers, 16-edge granularity)
    const int prepGrid = 385 + SCAN1_B + 256;         // transpose+prep+zero(cnt,pooled)

    transp_prep_kernel<<<prepGrid, 256, 0, stream>>>(W1b, W2b, W1a, W2a, W_enc, b_enc, W0, b0,
                                                     WT, wkey, bias0, cnt, pooled);
    encode_kernel<<<N_NODES / 2, 256, 0, stream>>>(x, W0, wkey, bias0, hbuf, xkey);

    // ---- merged CSR build (both layers; cnt zeroed by transp_prep) ----
    hist_kernel<<<bothGrid, 256, 0, stream>>>(dst1, dst2, cnt);
    scan1_kernel<<<SCAN1_B, 256, 0, stream>>>(cnt, cursor, partials);
    scan2_kernel<<<1, 1024, 0, stream>>>(partials);
    scatter_kernel<<<bothGrid, 256, 0, stream>>>(src1, dst1, src2, dst2, cursor, partials, pedge);
    zbound_both_kernel<<<zbGrid, 256, 0, stream>>>(pedge, agg1, agg2);

    // ---- layer 1 ----
    mm_mfma_dual_kernel<<<mmGrid, 256, 0, stream>>>(hbuf, nullptr, nullptr, nullptr, nullptr,
                                                    WuT1, WvT1, b1a, ubuf, vbuf, N_NODES);
    edge_kernel<<<EDGE_GRID, 512, 0, stream>>>(ubuf, vbuf, xkey, pedge, WbT1, W1a + 256 * HID, agg1);

    // ---- layer 2 (mm fuses layer-1 combine; writes x1 to hbuf) ----
    mm_mfma_dual_kernel<<<mmGrid, 256, 0, stream>>>(hbuf, agg1, cnt, b1b, hbuf,
                                                    WuT2, WvT2, b2a, ubuf, vbuf, N_NODES);
    edge_kernel<<<EDGE_GRID, 512, 0, stream>>>(ubuf, vbuf, xkey, pedge + N_EDGES, WbT2, W2a + 256 * HID, agg2);

    // ---- pooling (layer-2 combine fused; pooled zeroed by transp_prep) + head ----
    pool_kernel<<<N_GRAPHS * 8, 256, 0, stream>>>(hbuf, agg2, b2b, cnt + N_NODES, batch, pooled);
    final_kernel<<<N_GRAPHS, 128, 0, stream>>>(pooled, batch, Wf1, bf1, Wf2, bf2, (float*)d_out);
}

// Round 6
// 671.726 us; speedup vs baseline: 1.0180x; 1.0180x over previous
//
#include <hip/hip_runtime.h>
#include <cstdint>

#define N_NODES 100000
#define N_EDGES 500000
#define N_GRAPHS 128
#define HID 128
#define SCAN1_B ((2 * N_NODES + 255) / 256)   // 782 blocks over concatenated counts
#define N_SEG (N_EDGES / 16)                  // 31250 16-edge segments per layer (phase-3 quarter granularity)
#define EDGE_GRID 512                         // persistent edge blocks: 2/CU x 256 CU

typedef __attribute__((ext_vector_type(8))) short short8;
typedef __attribute__((ext_vector_type(4))) float f32x4;

// ---- raw workgroup barrier: drains LDS only, leaves VMEM in flight ----
__device__ __forceinline__ void wg_barrier() {
    asm volatile("s_waitcnt lgkmcnt(0)\n\ts_barrier" ::: "memory");
}

// ---- monotone float<->uint encoding for max; enc==0 marks "never written" ----
__device__ __forceinline__ unsigned encf(float f) {
    unsigned u = __float_as_uint(f);
    return (u & 0x80000000u) ? ~u : (u | 0x80000000u);
}
__device__ __forceinline__ float decf(unsigned e) {
    unsigned u = (e & 0x80000000u) ? (e & 0x7FFFFFFFu) : ~e;
    return __uint_as_float(u);
}
__device__ __forceinline__ unsigned pk_bf16(float a, float b) {
    unsigned ua = __float_as_uint(a);
    unsigned ub = __float_as_uint(b);
    ua = (ua + 0x7fffu + ((ua >> 16) & 1u)) >> 16;
    ub = (ub + 0x7fffu + ((ub >> 16) & 1u)) & 0xffff0000u;
    return ua | ub;
}
__device__ __forceinline__ ushort bf16r(float f) {
    unsigned u = __float_as_uint(f);
    return (ushort)((u + 0x7fffu + ((u >> 16) & 1u)) >> 16);
}
__device__ __forceinline__ float bf2f(ushort h) {
    return __uint_as_float((unsigned)h << 16);
}

// ---- transpose+convert weights -> bf16 [n][k], D computed on the fly;
//      block 384 does the prep (wkey/bias0); blocks >=385 zero cnt + pooled ----
__global__ __launch_bounds__(256) void transp_prep_kernel(const float* __restrict__ W1b,
                                                          const float* __restrict__ W2b,
                                                          const float* __restrict__ W1a,
                                                          const float* __restrict__ W2a,
                                                          const float* __restrict__ W_enc,
                                                          const float* __restrict__ b_enc,
                                                          const float* __restrict__ W0,
                                                          const float* __restrict__ b0,
                                                          ushort* __restrict__ WT,
                                                          float* __restrict__ wkey,
                                                          float* __restrict__ bias0,
                                                          int* __restrict__ cnt,
                                                          float* __restrict__ pooled) {
    int blk = blockIdx.x;
    int tid = threadIdx.x;
    if (blk >= 385) {   // zeroing duty: 782 blocks for cnt, 256 for pooled
        int z = blk - 385;
        if (z < SCAN1_B) {
            int i = z * 256 + tid;
            if (i < 2 * N_NODES) cnt[i] = 0;
        } else {
            int i = (z - SCAN1_B) * 256 + tid;   // exactly 128*512 = 65536 floats
            pooled[i] = 0.f;
        }
        return;
    }
    if (blk == 384) {   // prep
        if (tid < HID) {
            float wk = 0.f, bk = b0[tid];
            for (int k = 0; k < 32; ++k) {
                float w = W0[(15 + k) * HID + tid];
                wk += W_enc[k] * w;
                bk += b_enc[k] * w;
            }
            wkey[tid] = wk;
            bias0[tid] = bk;
        }
        return;
    }
    int m = blk >> 6;
    int i = (blk & 63) * 256 + tid;   // i = n*128 + k
    int n = i >> 7, k = i & 127;
    int src = k * HID + n;
    float v;
    switch (m) {
        case 0: v = W1b[src]; break;
        case 1: v = W2b[src]; break;
        case 2: v = W1a[src]; break;
        case 3: v = W1a[HID * HID + src] - W1a[src]; break;
        case 4: v = W2a[src]; break;
        default: v = W2a[HID * HID + src] - W2a[src]; break;
    }
    WT[m * HID * HID + i] = bf16r(v);
}

// ---- encoder: h = relu(features @ W0[0:15] + key*wkey + bias0) -> bf16;
//      also emits dense xkey[n] = x[n*16] for the edge kernels ----
__global__ __launch_bounds__(256) void encode_kernel(const float* __restrict__ x,
                                                     const float* __restrict__ W0,
                                                     const float* __restrict__ wkey,
                                                     const float* __restrict__ bias0,
                                                     ushort* __restrict__ h,
                                                     float* __restrict__ xkey) {
    int n = blockIdx.x * 2 + (threadIdx.x >> 7);
    int j = threadIdx.x & 127;
    const float* xr = x + n * 16;
    float k0 = xr[0];
    if (j == 0) xkey[n] = k0;
    float acc = bias0[j] + k0 * wkey[j];
#pragma unroll
    for (int f = 0; f < 15; ++f)
        acc = fmaf(xr[1 + f], W0[f * HID + j], acc);
    h[n * HID + j] = bf16r(fmaxf(acc, 0.f));
}

// ---- dual MFMA (N x 128 bf16) @ (128 x 128) -> bf16, LDS-restaged epilogue ----
__global__ __launch_bounds__(256, 4) void mm_mfma_dual_kernel(const ushort* __restrict__ in,
                                                              const unsigned* __restrict__ aggin,
                                                              const int* __restrict__ cntin,
                                                              const float* __restrict__ baddin,
                                                              ushort* __restrict__ xout,
                                                              const ushort* __restrict__ WuT,
                                                              const ushort* __restrict__ WvT,
                                                              const float* __restrict__ bv,
                                                              ushort* __restrict__ outu,
                                                              ushort* __restrict__ outv, int nrows) {
    __shared__ ushort sH[128 * 136];   // A-tile, then reused for D-restage
    int tid = threadIdx.x;
    int n0 = blockIdx.x * 128;
#pragma unroll
    for (int q = 0; q < 8; ++q) {
        int c = q * 256 + tid;
        int r = c >> 4, off = (c & 15) << 3;
        int n = n0 + r;
        uint4 vv = make_uint4(0, 0, 0, 0);
        if (n < nrows) {
            uint4 hv = *(const uint4*)(in + (size_t)n * HID + off);
            if (aggin) {
                float add[8];
#pragma unroll
                for (int p = 0; p < 8; ++p) add[p] = 0.f;
                if (cntin[n] > 0) {
                    uint4 e0 = *(const uint4*)(aggin + (size_t)n * HID + off);
                    uint4 e1 = *(const uint4*)(aggin + (size_t)n * HID + off + 4);
                    float4 bb0 = *(const float4*)(baddin + off);
                    float4 bb1 = *(const float4*)(baddin + off + 4);
                    add[0] = decf(e0.x) + bb0.x; add[1] = decf(e0.y) + bb0.y;
                    add[2] = decf(e0.z) + bb0.z; add[3] = decf(e0.w) + bb0.w;
                    add[4] = decf(e1.x) + bb1.x; add[5] = decf(e1.y) + bb1.y;
                    add[6] = decf(e1.z) + bb1.z; add[7] = decf(e1.w) + bb1.w;
                }
                unsigned hw[4] = {hv.x, hv.y, hv.z, hv.w};
                unsigned ow[4];
#pragma unroll
                for (int p = 0; p < 4; ++p) {
                    float lo = __uint_as_float(hw[p] << 16);
                    float hi = __uint_as_float(hw[p] & 0xffff0000u);
                    float r0 = fmaxf(add[2 * p] + lo, 0.f);
                    float r1 = fmaxf(add[2 * p + 1] + hi, 0.f);
                    ow[p] = pk_bf16(r0, r1);
                }
                vv = make_uint4(ow[0], ow[1], ow[2], ow[3]);
                *(uint4*)(xout + (size_t)n * HID + off) = vv;
            } else {
                vv = hv;
            }
        }
        *(uint4*)(sH + r * 136 + off) = vv;
    }
    __syncthreads();

    int lane = tid & 63, wv = tid >> 6;
    int l15 = lane & 15, quad = lane >> 4;

    short8 afr[2][4];
#pragma unroll
    for (int rr = 0; rr < 2; ++rr) {
        const ushort* ab = sH + (wv * 32 + rr * 16 + l15) * 136 + quad * 8;
#pragma unroll
        for (int kc = 0; kc < 4; ++kc)
            afr[rr][kc] = *(const short8*)(ab + kc * 32);
    }

#pragma unroll
    for (int pass = 0; pass < 2; ++pass) {
        const ushort* WT = pass ? WvT : WuT;
        ushort* out = pass ? outv : outu;
        f32x4 acc[2][8];
#pragma unroll
        for (int rr = 0; rr < 2; ++rr)
#pragma unroll
            for (int ct = 0; ct < 8; ++ct) acc[rr][ct] = (f32x4){0.f, 0.f, 0.f, 0.f};
#pragma unroll
        for (int kc = 0; kc < 4; ++kc) {
#pragma unroll
            for (int ct = 0; ct < 8; ++ct) {
                short8 bfr = *(const short8*)(WT + (ct * 16 + l15) * 128 + quad * 8 + kc * 32);
                acc[0][ct] = __builtin_amdgcn_mfma_f32_16x16x32_bf16(afr[0][kc], bfr, acc[0][ct], 0, 0, 0);
                acc[1][ct] = __builtin_amdgcn_mfma_f32_16x16x32_bf16(afr[1][kc], bfr, acc[1][ct], 0, 0, 0);
            }
        }
        __syncthreads();
#pragma unroll
        for (int ct = 0; ct < 8; ++ct) {
            int col = ct * 16 + l15;
            float bb = pass ? bv[col] : 0.f;
#pragma unroll
            for (int rr = 0; rr < 2; ++rr) {
                int rowb = wv * 32 + rr * 16 + quad * 4;
#pragma unroll
                for (int reg = 0; reg < 4; ++reg)
                    sH[(rowb + reg) * 136 + col] = bf16r(acc[rr][ct][reg] + bb);
            }
        }
        __syncthreads();
#pragma unroll
        for (int q = 0; q < 8; ++q) {
            int c = q * 256 + tid;
            int r = c >> 4, off = (c & 15) << 3;
            int m = n0 + r;
            if (m < nrows)
                *(uint4*)(out + (size_t)m * HID + off) = *(const uint4*)(sH + r * 136 + off);
        }
    }
}

// ---- merged CSR build for BOTH layers ----
__global__ __launch_bounds__(256) void hist_kernel(const int* __restrict__ dst1,
                                                   const int* __restrict__ dst2,
                                                   int* __restrict__ cnt) {
    int e = blockIdx.x * 256 + threadIdx.x;
    if (e < N_EDGES) atomicAdd(&cnt[dst1[e]], 1);
    else if (e < 2 * N_EDGES) atomicAdd(&cnt[N_NODES + dst2[e - N_EDGES]], 1);
}

__global__ __launch_bounds__(256) void scan1_kernel(const int* __restrict__ cnt,
                                                    int* __restrict__ cursor,
                                                    int* __restrict__ partials) {
    __shared__ int tmp[256];
    int tid = threadIdx.x;
    int gid = blockIdx.x * 256 + tid;
    int v = (gid < 2 * N_NODES) ? cnt[gid] : 0;
    tmp[tid] = v;
    __syncthreads();
#pragma unroll
    for (int off = 1; off < 256; off <<= 1) {
        int t = (tid >= off) ? tmp[tid - off] : 0;
        __syncthreads();
        tmp[tid] += t;
        __syncthreads();
    }
    if (gid < 2 * N_NODES) cursor[gid] = tmp[tid] - v;   // local exclusive
    if (tid == 255) partials[blockIdx.x] = tmp[255];
}

__global__ __launch_bounds__(1024) void scan2_kernel(int* __restrict__ partials) {
    __shared__ int tmp[1024];
    int tid = threadIdx.x;
    int v = (tid < SCAN1_B) ? partials[tid] : 0;
    tmp[tid] = v;
    __syncthreads();
#pragma unroll
    for (int off = 1; off < 1024; off <<= 1) {
        int t = (tid >= off) ? tmp[tid - off] : 0;
        __syncthreads();
        tmp[tid] += t;
        __syncthreads();
    }
    if (tid < SCAN1_B) partials[tid] = tmp[tid] - v;  // exclusive
}

__global__ __launch_bounds__(256) void scatter_kernel(const int* __restrict__ src1,
                                                      const int* __restrict__ dst1,
                                                      const int* __restrict__ src2,
                                                      const int* __restrict__ dst2,
                                                      int* __restrict__ cursor,
                                                      const int* __restrict__ partials,
                                                      int2* __restrict__ pedge) {
    int e = blockIdx.x * 256 + threadIdx.x;
    if (e < N_EDGES) {
        int d = dst1[e];
        int pos = atomicAdd(&cursor[d], 1) + partials[d >> 8];
        pedge[pos] = make_int2(src1[e], d);
    } else if (e < 2 * N_EDGES) {
        int d = dst2[e - N_EDGES];
        int idx = N_NODES + d;
        int pos = atomicAdd(&cursor[idx], 1) + partials[idx >> 8];
        pedge[pos] = make_int2(src2[e - N_EDGES], d);   // pos lands in [N_EDGES, 2*N_EDGES)
    }
}

// ---- zero boundary agg rows for BOTH layers in one launch (u32 arrays).
//      16-edge granularity to match the phase-3 quarter size at window=64 ----
__global__ __launch_bounds__(256) void zbound_both_kernel(const int2* __restrict__ pedge,
                                                          unsigned* __restrict__ agg1,
                                                          unsigned* __restrict__ agg2) {
    int b = blockIdx.x * 4 + (threadIdx.x >> 6);
    int lane = threadIdx.x & 63;
    if (b >= 2 * N_SEG) return;
    int layer = b >= N_SEG;
    int bl = b - layer * N_SEG;
    const int2* pe = pedge + (size_t)layer * N_EDGES;
    unsigned* agg = layer ? agg2 : agg1;
    int d;
    if (bl == 0) {
        d = pe[N_EDGES - 1].y;               // tail row (clamped duplicates -> atomics)
    } else {
        int da = pe[bl * 16 - 1].y, db = pe[bl * 16].y;
        if (da != db) return;
        d = db;
    }
    *(uint2*)(agg + (size_t)d * HID + lane * 2) = make_uint2(0u, 0u);
}

// ---- edge conv: bf16 MFMA, 64-edge dst-sorted windows, 512 threads ----
// v7: the two structural costs identified by instruction arithmetic:
//  (1) B-fragments (constant weights!) were re-read from LDS every window
//      (256 B/thread/window, 4-8-way banked). Now loaded ONCE per persistent
//      block into 64 VGPRs; the MFMA loop is register-only for B. sWT gone.
//  (2) phase-3's serial 16-iter dst-walk was duplicated x128 threads.
//      Now wave 0 computes per-edge segment-head flags ONCE via __ballot,
//      broadcast via LDS + readfirstlane; column threads run a branch-light
//      unrolled max-scan with scalar (SALU) control flow.
__global__ __launch_bounds__(512, 4) void edge_kernel(const ushort* __restrict__ u,
                                                      const ushort* __restrict__ v,
                                                      const float* __restrict__ xkey,
                                                      const int2* __restrict__ pedge,
                                                      const ushort* __restrict__ WbT,
                                                      const float* __restrict__ wlast,
                                                      unsigned* __restrict__ agg) {
    __shared__ ushort sU[64 * 136];     // 17408 B union: t[64][136] then msgT[128][66]
    __shared__ int sDst[64];
    __shared__ int sBnd[2];             // [0]=dst before window, [1]=dst after window
    __shared__ unsigned sMask[3];       // head-flag mask lo/hi + head64 flag
    int tid = threadIdx.x;
    const int nwin = (N_EDGES + 63) >> 6;   // 7813
    const int gstep = EDGE_GRID;

    int eloc = tid >> 3;
    int sub = tid & 7;
    int kb = sub << 4;
    int lane = tid & 63, wv = tid >> 6;
    int l15 = lane & 15, quad = lane >> 4;
    int ch = wv & 1, rh = wv >> 1;

    // ---- B-fragments: loaded ONCE per block from global (L2-hot 32KB) into
    //      64 VGPRs. wave wv owns cols (wv&1)*64..+63 of the output.
    short8 breg[4][4];
#pragma unroll
    for (int kc = 0; kc < 4; ++kc)
#pragma unroll
        for (int ct = 0; ct < 4; ++ct)
            breg[kc][ct] = *(const short8*)(WbT + ((ch * 4 + ct) * 16 + l15) * 128 + quad * 8 + kc * 32);

    // loop-invariant wlast slice for this thread's 16 columns -> registers
    float wreg[16];
    {
        const float4* wr4 = (const float4*)(wlast + kb);
#pragma unroll
        for (int q = 0; q < 4; ++q) {
            float4 wq = wr4[q];
            wreg[q * 4 + 0] = wq.x; wreg[q * 4 + 1] = wq.y;
            wreg[q * 4 + 2] = wq.z; wreg[q * 4 + 3] = wq.w;
        }
    }

    for (int w = blockIdx.x; w < nwin; w += gstep) {
        int w0 = w * 64;

        // phase 1: per-thread meta + gather + compute t
        {
            int e = w0 + eloc;
            if (e >= N_EDGES) e = N_EDGES - 1;   // clamp: idempotent under max
            int2 sd = pedge[e];
            if (sub == 0) sDst[eloc] = sd.y;
            if (tid < 2) {
                int eb = (tid == 0) ? (w0 - 1) : (w0 + 64);
                sBnd[tid] = (eb >= 0 && eb < N_EDGES) ? pedge[eb].y : -1;
            }
            float kd = xkey[sd.x] - xkey[sd.y];
            const uint4* ur = (const uint4*)(u + (size_t)sd.x * HID + kb);
            const uint4* vr = (const uint4*)(v + (size_t)sd.y * HID + kb);
            uint4 uu[2], vvv[2];
            uu[0] = ur[0]; uu[1] = ur[1];
            vvv[0] = vr[0]; vvv[1] = vr[1];
#pragma unroll
            for (int q = 0; q < 2; ++q) {
                unsigned pu[4] = {uu[q].x, uu[q].y, uu[q].z, uu[q].w};
                unsigned pv[4] = {vvv[q].x, vvv[q].y, vvv[q].z, vvv[q].w};
                unsigned pk[4];
#pragma unroll
                for (int p = 0; p < 4; ++p) {
                    float a0 = __uint_as_float(pu[p] << 16) + __uint_as_float(pv[p] << 16);
                    float a1 = __uint_as_float(pu[p] & 0xffff0000u) + __uint_as_float(pv[p] & 0xffff0000u);
                    a0 = fmaf(kd, wreg[q * 8 + 2 * p], a0);
                    a1 = fmaf(kd, wreg[q * 8 + 2 * p + 1], a1);
                    a0 = fmaxf(a0, 0.1f * a0);   // leaky relu (valid for both signs)
                    a1 = fmaxf(a1, 0.1f * a1);
                    pk[p] = pk_bf16(a0, a1);
                }
                uint4 o; o.x = pk[0]; o.y = pk[1]; o.z = pk[2]; o.w = pk[3];
                *(uint4*)(sU + eloc * 136 + kb + q * 8) = o;
            }
        }
        wg_barrier();   // t + sDst + sBnd ready

        // segment head flags: computed ONCE by wave 0 (uniform across columns)
        if (tid < 64) {
            int dprev = (tid == 0) ? sBnd[0] : sDst[tid - 1];
            unsigned long long m = __ballot(sDst[tid] != dprev);
            if (tid == 0) { sMask[0] = (unsigned)m; sMask[1] = (unsigned)(m >> 32); }
            if (tid == 63) sMask[2] = (sDst[63] != sBnd[1]) ? 1u : 0u;
        }

        // phase 2: MFMA. wave wv: rows (wv>>1)*16..+15, cols (wv&1)*64..+63.
        // A from LDS, B from registers.
        short8 afr[4];
        {
            const ushort* ab = sU + (rh * 16 + l15) * 136 + quad * 8;
#pragma unroll
            for (int kc = 0; kc < 4; ++kc)
                afr[kc] = *(const short8*)(ab + kc * 32);
        }
        f32x4 acc[4];
#pragma unroll
        for (int ct = 0; ct < 4; ++ct) acc[ct] = (f32x4){0.f, 0.f, 0.f, 0.f};
#pragma unroll
        for (int kc = 0; kc < 4; ++kc) {
#pragma unroll
            for (int ct = 0; ct < 4; ++ct) {
                acc[ct] = __builtin_amdgcn_mfma_f32_16x16x32_bf16(afr[kc], breg[kc][ct], acc[ct], 0, 0, 0);
            }
        }
        wg_barrier();   // all t reads done -> sU reusable

        // epilogue: msgT[col][edge] bf16, stride 66
#pragma unroll
        for (int ct = 0; ct < 4; ++ct) {
            int col = (ch * 4 + ct) * 16 + l15;
            uint2 pr;
            pr.x = pk_bf16(acc[ct][0], acc[ct][1]);
            pr.y = pk_bf16(acc[ct][2], acc[ct][3]);
            *(uint2*)(sU + col * 66 + rh * 16 + quad * 4) = pr;
        }
        wg_barrier();

        // phase 3: mask-driven segmented max, 4 threads/col (16 edges each).
        // ext bit e3 = "edge base+e3 starts a new segment"; bit 16 = head at
        // the following quarter/window (so !bit16 = last segment continues).
        {
            int j = tid & 127;
            int q4 = tid >> 7;            // 0..3 (wave-uniform)
            int base = q4 * 16;
            const ushort* mrow = sU + j * 66 + base;
            float vals[16];
#pragma unroll
            for (int q = 0; q < 4; ++q) {
                ushort4 mv = *(const ushort4*)(mrow + q * 4);
                vals[q * 4 + 0] = bf2f(mv.x);
                vals[q * 4 + 1] = bf2f(mv.y);
                vals[q * 4 + 2] = bf2f(mv.z);
                vals[q * 4 + 3] = bf2f(mv.w);
            }
            unsigned mlo = __builtin_amdgcn_readfirstlane(sMask[0]);
            unsigned mhi = __builtin_amdgcn_readfirstlane(sMask[1]);
            unsigned b64 = __builtin_amdgcn_readfirstlane(sMask[2]);
            unsigned long long mask = ((unsigned long long)mhi << 32) | mlo;
            unsigned slice = (unsigned)((mask >> base) & 0xFFFFull);
            unsigned nextbit = (q4 == 3) ? (b64 & 1u) : (unsigned)((mask >> (base + 16)) & 1ull);
            unsigned ext = slice | (nextbit << 16);
            bool contFrom = !(ext & 1u);
            float run = 0.f;
            bool first = true;
#pragma unroll
            for (int e3 = 0; e3 < 16; ++e3) {
                float vv2 = vals[e3];
                bool hb = (ext >> e3) & 1u;
                run = (e3 == 0 || hb) ? vv2 : fmaxf(run, vv2);
                bool end = (e3 == 15) || ((ext >> (e3 + 1)) & 1u);
                if (end) {
                    int d = sDst[base + e3];
                    unsigned en = encf(run);
                    unsigned* ap = agg + (size_t)d * HID + j;
                    bool useAtomic = (first && contFrom) || ((e3 == 15) && !nextbit);
                    if (useAtomic) atomicMax(ap, en);
                    else *ap = en;
                    first = false;
                }
            }
        }
        wg_barrier();   // phase-3 sU/sDst/sMask reads done -> next iter overwrites
    }
}

// ---- pooling with fused layer-2 combine: x2 never materialized ----
__global__ __launch_bounds__(256) void pool_kernel(const ushort* __restrict__ x1,
                                                   const unsigned* __restrict__ agg2,
                                                   const float* __restrict__ b2b,
                                                   const int* __restrict__ cnt2,
                                                   const int* __restrict__ batch,
                                                   float* __restrict__ pooled) {
    int g = blockIdx.x >> 3, s = blockIdx.x & 7;
    int tid = threadIdx.x;
    int lo = 0, hi = N_NODES;
    while (lo < hi) { int mid = (lo + hi) >> 1; if (batch[mid] < g) lo = mid + 1; else hi = mid; }
    int start = lo;
    hi = N_NODES;
    while (lo < hi) { int mid = (lo + hi) >> 1; if (batch[mid] < g + 1) lo = mid + 1; else hi = mid; }
    int end = lo;
    int cnt = end - start;
    int b0 = start + (int)((long long)cnt * s / 8);
    int b1 = start + (int)((long long)cnt * (s + 1) / 8);
    if (b1 <= b0) return;
    int j = tid & 127;
    bool isx2 = tid >= 128;
    float bbj = isx2 ? b2b[j] : 0.f;
    float mx = -INFINITY, sm = 0.f;
    for (int n = b0; n < b1; ++n) {
        float xv = bf2f(x1[(size_t)n * HID + j]);
        float vv;
        if (isx2) {
            float a = 0.f;
            if (cnt2[n] > 0) a = decf(agg2[(size_t)n * HID + j]) + bbj;
            vv = fmaxf(a + xv, 0.f);
        } else {
            vv = xv;
        }
        mx = fmaxf(mx, vv);
        sm += vv;
    }
    atomicMax((unsigned*)pooled + (size_t)g * 512 + tid, encf(mx));
    atomicAdd(pooled + (size_t)g * 512 + 256 + tid, sm);
}

// ---- final MLP + log_softmax ----
__global__ __launch_bounds__(128) void final_kernel(const float* __restrict__ pooled,
                                                    const int* __restrict__ batch,
                                                    const float* __restrict__ Wf1,
                                                    const float* __restrict__ bf1,
                                                    const float* __restrict__ Wf2,
                                                    const float* __restrict__ bf2,
                                                    float* __restrict__ out) {
    __shared__ float sP[512];
    __shared__ float sH[128];
    int g = blockIdx.x, tid = threadIdx.x;
    int lo = 0, hi = N_NODES;
    while (lo < hi) { int mid = (lo + hi) >> 1; if (batch[mid] < g) lo = mid + 1; else hi = mid; }
    int start = lo;
    hi = N_NODES;
    while (lo < hi) { int mid = (lo + hi) >> 1; if (batch[mid] < g + 1) lo = mid + 1; else hi = mid; }
    int cnt = lo - start;
    float inv = 1.f / (float)(cnt > 1 ? cnt : 1);
#pragma unroll
    for (int q = 0; q < 4; ++q) {
        int idx = q * 128 + tid;
        float raw;
        if (idx < 256) {
            unsigned e = ((const unsigned*)pooled)[(size_t)g * 512 + idx];
            raw = (e == 0u) ? 0.f : decf(e);
        } else {
            raw = pooled[(size_t)g * 512 + idx] * inv;
        }
        sP[idx] = raw;
    }
    __syncthreads();
    float acc = bf1[tid];
    for (int k = 0; k < 512; ++k) acc = fmaf(sP[k], Wf1[k * HID + tid], acc);
    sH[tid] = fmaxf(acc, 0.f);
    __syncthreads();
    if (tid < 2) {
        float l = bf2[tid];
        for (int k = 0; k < 128; ++k) l = fmaf(sH[k], Wf2[k * 2 + tid], l);
        sP[tid] = l;
    }
    __syncthreads();
    if (tid == 0) {
        float l0 = sP[0], l1 = sP[1];
        float m = fmaxf(l0, l1);
        float ls = m + logf(expf(l0 - m) + expf(l1 - m));
        out[g * 2 + 0] = l0 - ls;
        out[g * 2 + 1] = l1 - ls;
    }
}

extern "C" void kernel_launch(void* const* d_in, const int* in_sizes, int n_in,
                              void* d_out, int out_size, void* d_ws, size_t ws_size,
                              hipStream_t stream) {
    const float* x     = (const float*)d_in[0];
    const float* W_enc = (const float*)d_in[1];
    const float* b_enc = (const float*)d_in[2];
    const float* W0    = (const float*)d_in[3];
    const float* b0    = (const float*)d_in[4];
    const float* W1a   = (const float*)d_in[5];
    const float* b1a   = (const float*)d_in[6];
    const float* W1b   = (const float*)d_in[7];
    const float* b1b   = (const float*)d_in[8];
    const float* W2a   = (const float*)d_in[9];
    const float* b2a   = (const float*)d_in[10];
    const float* W2b   = (const float*)d_in[11];
    const float* b2b   = (const float*)d_in[12];
    const float* Wf1   = (const float*)d_in[13];
    const float* bf1   = (const float*)d_in[14];
    const float* Wf2   = (const float*)d_in[15];
    const float* bf2   = (const float*)d_in[16];
    const int* src1    = (const int*)d_in[17];
    const int* dst1    = (const int*)d_in[18];
    const int* src2    = (const int*)d_in[19];
    const int* dst2    = (const int*)d_in[20];
    const int* batch   = (const int*)d_in[21];

    const size_t NB = (size_t)N_NODES * HID;     // 12.8M elements
    ushort* hbuf  = (ushort*)d_ws;               // h -> x1 (in place, bf16)
    unsigned* agg1 = (unsigned*)(hbuf + NB);     // layer-1 segment-max (u32 encoded)
    unsigned* agg2 = agg1 + NB;                  // layer-2 segment-max
    ushort* ubuf  = (ushort*)(agg2 + NB);        // u bf16
    ushort* vbuf  = ubuf + NB;                   // v bf16
    ushort* WT    = vbuf + NB;                   // 6 x 16384 bf16: Wb1,Wb2,Wu1,Wv1,Wu2,Wv2
    ushort* WbT1 = WT;
    ushort* WbT2 = WT + 1 * HID * HID;
    ushort* WuT1 = WT + 2 * HID * HID;
    ushort* WvT1 = WT + 3 * HID * HID;
    ushort* WuT2 = WT + 4 * HID * HID;
    ushort* WvT2 = WT + 5 * HID * HID;
    float* wkey  = (float*)(WT + 6 * HID * HID);
    float* bias0 = wkey + 128;
    float* xkey  = bias0 + 128;                  // dense per-node key (N_NODES fp32)
    float* pooled = xkey + N_NODES;              // 128*512 fp32
    int* cnt    = (int*)(pooled + 128 * 512);    // 2*N_NODES (both layers)
    int* cursor = cnt + 2 * N_NODES;             // 2*N_NODES
    int* partials = cursor + 2 * N_NODES;        // 1024
    int2* pedge = (int2*)(partials + 1024);      // 2*N_EDGES pairs (both layers)

    const int bothGrid = (2 * N_EDGES + 255) / 256;   // 3907
    const int mmGrid   = (N_NODES + 127) / 128;       // 782
    const int zbGrid   = (2 * N_SEG + 3) / 4;         // 15626 (both layers, 16-edge granularity)
    const int prepGrid = 385 + SCAN1_B + 256;         // transpose+prep+zero(cnt,pooled)

    transp_prep_kernel<<<prepGrid, 256, 0, stream>>>(W1b, W2b, W1a, W2a, W_enc, b_enc, W0, b0,
                                                     WT, wkey, bias0, cnt, pooled);
    encode_kernel<<<N_NODES / 2, 256, 0, stream>>>(x, W0, wkey, bias0, hbuf, xkey);

    // ---- merged CSR build (both layers; cnt zeroed by transp_prep) ----
    hist_kernel<<<bothGrid, 256, 0, stream>>>(dst1, dst2, cnt);
    scan1_kernel<<<SCAN1_B, 256, 0, stream>>>(cnt, cursor, partials);
    scan2_kernel<<<1, 1024, 0, stream>>>(partials);
    scatter_kernel<<<bothGrid, 256, 0, stream>>>(src1, dst1, src2, dst2, cursor, partials, pedge);
    zbound_both_kernel<<<zbGrid, 256, 0, stream>>>(pedge, agg1, agg2);

    // ---- layer 1 ----
    mm_mfma_dual_kernel<<<mmGrid, 256, 0, stream>>>(hbuf, nullptr, nullptr, nullptr, nullptr,
                                                    WuT1, WvT1, b1a, ubuf, vbuf, N_NODES);
    edge_kernel<<<EDGE_GRID, 512, 0, stream>>>(ubuf, vbuf, xkey, pedge, WbT1, W1a + 256 * HID, agg1);

    // ---- layer 2 (mm fuses layer-1 combine; writes x1 to hbuf) ----
    mm_mfma_dual_kernel<<<mmGrid, 256, 0, stream>>>(hbuf, agg1, cnt, b1b, hbuf,
                                                    WuT2, WvT2, b2a, ubuf, vbuf, N_NODES);
    edge_kernel<<<EDGE_GRID, 512, 0, stream>>>(ubuf, vbuf, xkey, pedge + N_EDGES, WbT2, W2a + 256 * HID, agg2);

    // ---- pooling (layer-2 combine fused; pooled zeroed by transp_prep) + head ----
    pool_kernel<<<N_GRAPHS * 8, 256, 0, stream>>>(hbuf, agg2, b2b, cnt + N_NODES, batch, pooled);
    final_kernel<<<N_GRAPHS, 128, 0, stream>>>(pooled, batch, Wf1, bf1, Wf2, bf2, (float*)d_out);
}

// Round 7
// 621.216 us; speedup vs baseline: 1.1008x; 1.0813x over previous
//
#include <hip/hip_runtime.h>
#include <cstdint>

#define N_NODES 100000
#define N_EDGES 500000
#define N_GRAPHS 128
#define HID 128
#define SCAN1_B ((2 * N_NODES + 255) / 256)   // 782 blocks over concatenated counts
#define N_SEG (N_EDGES / 16)                  // 31250 16-edge segments per layer (phase-3 quarter granularity)

typedef __attribute__((ext_vector_type(8))) short short8;
typedef __attribute__((ext_vector_type(4))) float f32x4;

// ---- monotone float<->uint encoding for max; enc==0 marks "never written" ----
__device__ __forceinline__ unsigned encf(float f) {
    unsigned u = __float_as_uint(f);
    return (u & 0x80000000u) ? ~u : (u | 0x80000000u);
}
__device__ __forceinline__ float decf(unsigned e) {
    unsigned u = (e & 0x80000000u) ? (e & 0x7FFFFFFFu) : ~e;
    return __uint_as_float(u);
}
__device__ __forceinline__ unsigned pk_bf16(float a, float b) {
    unsigned ua = __float_as_uint(a);
    unsigned ub = __float_as_uint(b);
    ua = (ua + 0x7fffu + ((ua >> 16) & 1u)) >> 16;
    ub = (ub + 0x7fffu + ((ub >> 16) & 1u)) & 0xffff0000u;
    return ua | ub;
}
__device__ __forceinline__ ushort bf16r(float f) {
    unsigned u = __float_as_uint(f);
    return (ushort)((u + 0x7fffu + ((u >> 16) & 1u)) >> 16);
}
__device__ __forceinline__ float bf2f(ushort h) {
    return __uint_as_float((unsigned)h << 16);
}

// ---- transpose+convert weights -> bf16 [n][k], D computed on the fly;
//      block 384 does the prep (wkey/bias0); blocks >=385 zero cnt + pooled ----
__global__ __launch_bounds__(256) void transp_prep_kernel(const float* __restrict__ W1b,
                                                          const float* __restrict__ W2b,
                                                          const float* __restrict__ W1a,
                                                          const float* __restrict__ W2a,
                                                          const float* __restrict__ W_enc,
                                                          const float* __restrict__ b_enc,
                                                          const float* __restrict__ W0,
                                                          const float* __restrict__ b0,
                                                          ushort* __restrict__ WT,
                                                          float* __restrict__ wkey,
                                                          float* __restrict__ bias0,
                                                          int* __restrict__ cnt,
                                                          float* __restrict__ pooled) {
    int blk = blockIdx.x;
    int tid = threadIdx.x;
    if (blk >= 385) {   // zeroing duty: 782 blocks for cnt, 256 for pooled
        int z = blk - 385;
        if (z < SCAN1_B) {
            int i = z * 256 + tid;
            if (i < 2 * N_NODES) cnt[i] = 0;
        } else {
            int i = (z - SCAN1_B) * 256 + tid;   // exactly 128*512 = 65536 floats
            pooled[i] = 0.f;
        }
        return;
    }
    if (blk == 384) {   // prep
        if (tid < HID) {
            float wk = 0.f, bk = b0[tid];
            for (int k = 0; k < 32; ++k) {
                float w = W0[(15 + k) * HID + tid];
                wk += W_enc[k] * w;
                bk += b_enc[k] * w;
            }
            wkey[tid] = wk;
            bias0[tid] = bk;
        }
        return;
    }
    int m = blk >> 6;
    int i = (blk & 63) * 256 + tid;   // i = n*128 + k
    int n = i >> 7, k = i & 127;
    int src = k * HID + n;
    float v;
    switch (m) {
        case 0: v = W1b[src]; break;
        case 1: v = W2b[src]; break;
        case 2: v = W1a[src]; break;
        case 3: v = W1a[HID * HID + src] - W1a[src]; break;
        case 4: v = W2a[src]; break;
        default: v = W2a[HID * HID + src] - W2a[src]; break;
    }
    WT[m * HID * HID + i] = bf16r(v);
}

// ---- encoder: h = relu(features @ W0[0:15] + key*wkey + bias0) -> bf16;
//      also emits dense xkey[n] = x[n*16] for the edge kernels ----
__global__ __launch_bounds__(256) void encode_kernel(const float* __restrict__ x,
                                                     const float* __restrict__ W0,
                                                     const float* __restrict__ wkey,
                                                     const float* __restrict__ bias0,
                                                     ushort* __restrict__ h,
                                                     float* __restrict__ xkey) {
    int n = blockIdx.x * 2 + (threadIdx.x >> 7);
    int j = threadIdx.x & 127;
    const float* xr = x + n * 16;
    float k0 = xr[0];
    if (j == 0) xkey[n] = k0;
    float acc = bias0[j] + k0 * wkey[j];
#pragma unroll
    for (int f = 0; f < 15; ++f)
        acc = fmaf(xr[1 + f], W0[f * HID + j], acc);
    h[n * HID + j] = bf16r(fmaxf(acc, 0.f));
}

// ---- dual MFMA (N x 128 bf16) @ (128 x 128) -> bf16, LDS-restaged epilogue ----
__global__ __launch_bounds__(256, 4) void mm_mfma_dual_kernel(const ushort* __restrict__ in,
                                                              const unsigned* __restrict__ aggin,
                                                              const int* __restrict__ cntin,
                                                              const float* __restrict__ baddin,
                                                              ushort* __restrict__ xout,
                                                              const ushort* __restrict__ WuT,
                                                              const ushort* __restrict__ WvT,
                                                              const float* __restrict__ bv,
                                                              ushort* __restrict__ outu,
                                                              ushort* __restrict__ outv, int nrows) {
    __shared__ ushort sH[128 * 136];   // A-tile, then reused for D-restage
    int tid = threadIdx.x;
    int n0 = blockIdx.x * 128;
#pragma unroll
    for (int q = 0; q < 8; ++q) {
        int c = q * 256 + tid;
        int r = c >> 4, off = (c & 15) << 3;
        int n = n0 + r;
        uint4 vv = make_uint4(0, 0, 0, 0);
        if (n < nrows) {
            uint4 hv = *(const uint4*)(in + (size_t)n * HID + off);
            if (aggin) {
                float add[8];
#pragma unroll
                for (int p = 0; p < 8; ++p) add[p] = 0.f;
                if (cntin[n] > 0) {
                    uint4 e0 = *(const uint4*)(aggin + (size_t)n * HID + off);
                    uint4 e1 = *(const uint4*)(aggin + (size_t)n * HID + off + 4);
                    float4 bb0 = *(const float4*)(baddin + off);
                    float4 bb1 = *(const float4*)(baddin + off + 4);
                    add[0] = decf(e0.x) + bb0.x; add[1] = decf(e0.y) + bb0.y;
                    add[2] = decf(e0.z) + bb0.z; add[3] = decf(e0.w) + bb0.w;
                    add[4] = decf(e1.x) + bb1.x; add[5] = decf(e1.y) + bb1.y;
                    add[6] = decf(e1.z) + bb1.z; add[7] = decf(e1.w) + bb1.w;
                }
                unsigned hw[4] = {hv.x, hv.y, hv.z, hv.w};
                unsigned ow[4];
#pragma unroll
                for (int p = 0; p < 4; ++p) {
                    float lo = __uint_as_float(hw[p] << 16);
                    float hi = __uint_as_float(hw[p] & 0xffff0000u);
                    float r0 = fmaxf(add[2 * p] + lo, 0.f);
                    float r1 = fmaxf(add[2 * p + 1] + hi, 0.f);
                    ow[p] = pk_bf16(r0, r1);
                }
                vv = make_uint4(ow[0], ow[1], ow[2], ow[3]);
                *(uint4*)(xout + (size_t)n * HID + off) = vv;
            } else {
                vv = hv;
            }
        }
        *(uint4*)(sH + r * 136 + off) = vv;
    }
    __syncthreads();

    int lane = tid & 63, wv = tid >> 6;
    int l15 = lane & 15, quad = lane >> 4;

    short8 afr[2][4];
#pragma unroll
    for (int rr = 0; rr < 2; ++rr) {
        const ushort* ab = sH + (wv * 32 + rr * 16 + l15) * 136 + quad * 8;
#pragma unroll
        for (int kc = 0; kc < 4; ++kc)
            afr[rr][kc] = *(const short8*)(ab + kc * 32);
    }

#pragma unroll
    for (int pass = 0; pass < 2; ++pass) {
        const ushort* WT = pass ? WvT : WuT;
        ushort* out = pass ? outv : outu;
        f32x4 acc[2][8];
#pragma unroll
        for (int rr = 0; rr < 2; ++rr)
#pragma unroll
            for (int ct = 0; ct < 8; ++ct) acc[rr][ct] = (f32x4){0.f, 0.f, 0.f, 0.f};
#pragma unroll
        for (int kc = 0; kc < 4; ++kc) {
#pragma unroll
            for (int ct = 0; ct < 8; ++ct) {
                short8 bfr = *(const short8*)(WT + (ct * 16 + l15) * 128 + quad * 8 + kc * 32);
                acc[0][ct] = __builtin_amdgcn_mfma_f32_16x16x32_bf16(afr[0][kc], bfr, acc[0][ct], 0, 0, 0);
                acc[1][ct] = __builtin_amdgcn_mfma_f32_16x16x32_bf16(afr[1][kc], bfr, acc[1][ct], 0, 0, 0);
            }
        }
        __syncthreads();
#pragma unroll
        for (int ct = 0; ct < 8; ++ct) {
            int col = ct * 16 + l15;
            float bb = pass ? bv[col] : 0.f;
#pragma unroll
            for (int rr = 0; rr < 2; ++rr) {
                int rowb = wv * 32 + rr * 16 + quad * 4;
#pragma unroll
                for (int reg = 0; reg < 4; ++reg)
                    sH[(rowb + reg) * 136 + col] = bf16r(acc[rr][ct][reg] + bb);
            }
        }
        __syncthreads();
#pragma unroll
        for (int q = 0; q < 8; ++q) {
            int c = q * 256 + tid;
            int r = c >> 4, off = (c & 15) << 3;
            int m = n0 + r;
            if (m < nrows)
                *(uint4*)(out + (size_t)m * HID + off) = *(const uint4*)(sH + r * 136 + off);
        }
    }
}

// ---- merged CSR build for BOTH layers ----
__global__ __launch_bounds__(256) void hist_kernel(const int* __restrict__ dst1,
                                                   const int* __restrict__ dst2,
                                                   int* __restrict__ cnt) {
    int e = blockIdx.x * 256 + threadIdx.x;
    if (e < N_EDGES) atomicAdd(&cnt[dst1[e]], 1);
    else if (e < 2 * N_EDGES) atomicAdd(&cnt[N_NODES + dst2[e - N_EDGES]], 1);
}

__global__ __launch_bounds__(256) void scan1_kernel(const int* __restrict__ cnt,
                                                    int* __restrict__ cursor,
                                                    int* __restrict__ partials) {
    __shared__ int tmp[256];
    int tid = threadIdx.x;
    int gid = blockIdx.x * 256 + tid;
    int v = (gid < 2 * N_NODES) ? cnt[gid] : 0;
    tmp[tid] = v;
    __syncthreads();
#pragma unroll
    for (int off = 1; off < 256; off <<= 1) {
        int t = (tid >= off) ? tmp[tid - off] : 0;
        __syncthreads();
        tmp[tid] += t;
        __syncthreads();
    }
    if (gid < 2 * N_NODES) cursor[gid] = tmp[tid] - v;   // local exclusive
    if (tid == 255) partials[blockIdx.x] = tmp[255];
}

__global__ __launch_bounds__(1024) void scan2_kernel(int* __restrict__ partials) {
    __shared__ int tmp[1024];
    int tid = threadIdx.x;
    int v = (tid < SCAN1_B) ? partials[tid] : 0;
    tmp[tid] = v;
    __syncthreads();
#pragma unroll
    for (int off = 1; off < 1024; off <<= 1) {
        int t = (tid >= off) ? tmp[tid - off] : 0;
        __syncthreads();
        tmp[tid] += t;
        __syncthreads();
    }
    if (tid < SCAN1_B) partials[tid] = tmp[tid] - v;  // exclusive
}

__global__ __launch_bounds__(256) void scatter_kernel(const int* __restrict__ src1,
                                                      const int* __restrict__ dst1,
                                                      const int* __restrict__ src2,
                                                      const int* __restrict__ dst2,
                                                      int* __restrict__ cursor,
                                                      const int* __restrict__ partials,
                                                      int2* __restrict__ pedge) {
    int e = blockIdx.x * 256 + threadIdx.x;
    if (e < N_EDGES) {
        int d = dst1[e];
        int pos = atomicAdd(&cursor[d], 1) + partials[d >> 8];
        pedge[pos] = make_int2(src1[e], d);
    } else if (e < 2 * N_EDGES) {
        int d = dst2[e - N_EDGES];
        int idx = N_NODES + d;
        int pos = atomicAdd(&cursor[idx], 1) + partials[idx >> 8];
        pedge[pos] = make_int2(src2[e - N_EDGES], d);   // pos lands in [N_EDGES, 2*N_EDGES)
    }
}

// ---- zero boundary agg rows for BOTH layers in one launch (u32 arrays).
//      16-edge granularity to match the phase-3 quarter size at window=64 ----
__global__ __launch_bounds__(256) void zbound_both_kernel(const int2* __restrict__ pedge,
                                                          unsigned* __restrict__ agg1,
                                                          unsigned* __restrict__ agg2) {
    int b = blockIdx.x * 4 + (threadIdx.x >> 6);
    int lane = threadIdx.x & 63;
    if (b >= 2 * N_SEG) return;
    int layer = b >= N_SEG;
    int bl = b - layer * N_SEG;
    const int2* pe = pedge + (size_t)layer * N_EDGES;
    unsigned* agg = layer ? agg2 : agg1;
    int d;
    if (bl == 0) {
        d = pe[N_EDGES - 1].y;               // tail row (clamped duplicates -> atomics)
    } else {
        int da = pe[bl * 16 - 1].y, db = pe[bl * 16].y;
        if (da != db) return;
        d = db;
    }
    *(uint2*)(agg + (size_t)d * HID + lane * 2) = make_uint2(0u, 0u);
}

// ---- edge conv: bf16 MFMA, 64-edge dst-sorted windows, 512 threads ----
// v8 (consolidation): the persistent grid (R3-R6) capped residency at 2
// blocks/CU and cost ~8 us/dispatch; every best number came from the
// non-persistent 1-window-per-block shape. v8 = R2's proven base
// (non-persistent, LDS W-tile, 3 blocks/CU) + the independently-proven
// cheap wins: ballot/mask phase-3 (R6, ~150 fewer VALU inst/thread),
// dense xkey + wlast-in-registers (R4).
__global__ __launch_bounds__(512, 6) void edge_kernel(const ushort* __restrict__ u,
                                                      const ushort* __restrict__ v,
                                                      const float* __restrict__ xkey,
                                                      const int2* __restrict__ pedge,
                                                      const ushort* __restrict__ WbT,
                                                      const float* __restrict__ wlast,
                                                      unsigned* __restrict__ agg) {
    __shared__ ushort sWT[128 * 136];   // 34816 B: WbT[n][k] bf16, padded stride
    __shared__ ushort sU[64 * 136];     // 17408 B union: t[64][136] then msgT[128][66]
    __shared__ int sDst[64];
    __shared__ int sBnd[2];             // [0]=dst before window, [1]=dst after window
    __shared__ unsigned sMask[3];       // head-flag mask lo/hi + head64 flag
    int tid = threadIdx.x;
    int w0 = blockIdx.x * 64;

    // W stage: 2048 uint4 over 512 threads = 4 each (L2-hot 32KB)
#pragma unroll
    for (int q = 0; q < 4; ++q) {
        int c = q * 512 + tid;
        int n = c >> 4, off = (c & 15) << 3;
        *(uint4*)(sWT + n * 136 + off) = *(const uint4*)(WbT + n * 128 + off);
    }

    int eloc = tid >> 3;
    int sub = tid & 7;
    int kb = sub << 4;
    int lane = tid & 63, wv = tid >> 6;
    int l15 = lane & 15, quad = lane >> 4;
    int ch = wv & 1, rh = wv >> 1;

    // loop-invariant wlast slice for this thread's 16 columns -> registers
    float wreg[16];
    {
        const float4* wr4 = (const float4*)(wlast + kb);
#pragma unroll
        for (int q = 0; q < 4; ++q) {
            float4 wq = wr4[q];
            wreg[q * 4 + 0] = wq.x; wreg[q * 4 + 1] = wq.y;
            wreg[q * 4 + 2] = wq.z; wreg[q * 4 + 3] = wq.w;
        }
    }

    // phase 1: per-thread meta + gather + compute t
    {
        int e = w0 + eloc;
        if (e >= N_EDGES) e = N_EDGES - 1;   // clamp: idempotent under max
        int2 sd = pedge[e];
        if (sub == 0) sDst[eloc] = sd.y;
        if (tid < 2) {
            int eb = (tid == 0) ? (w0 - 1) : (w0 + 64);
            sBnd[tid] = (eb >= 0 && eb < N_EDGES) ? pedge[eb].y : -1;
        }
        float kd = xkey[sd.x] - xkey[sd.y];
        const uint4* ur = (const uint4*)(u + (size_t)sd.x * HID + kb);
        const uint4* vr = (const uint4*)(v + (size_t)sd.y * HID + kb);
        uint4 uu[2], vvv[2];
        uu[0] = ur[0]; uu[1] = ur[1];
        vvv[0] = vr[0]; vvv[1] = vr[1];
#pragma unroll
        for (int q = 0; q < 2; ++q) {
            unsigned pu[4] = {uu[q].x, uu[q].y, uu[q].z, uu[q].w};
            unsigned pv[4] = {vvv[q].x, vvv[q].y, vvv[q].z, vvv[q].w};
            unsigned pk[4];
#pragma unroll
            for (int p = 0; p < 4; ++p) {
                float a0 = __uint_as_float(pu[p] << 16) + __uint_as_float(pv[p] << 16);
                float a1 = __uint_as_float(pu[p] & 0xffff0000u) + __uint_as_float(pv[p] & 0xffff0000u);
                a0 = fmaf(kd, wreg[q * 8 + 2 * p], a0);
                a1 = fmaf(kd, wreg[q * 8 + 2 * p + 1], a1);
                a0 = fmaxf(a0, 0.1f * a0);   // leaky relu
                a1 = fmaxf(a1, 0.1f * a1);
                pk[p] = pk_bf16(a0, a1);
            }
            uint4 o; o.x = pk[0]; o.y = pk[1]; o.z = pk[2]; o.w = pk[3];
            *(uint4*)(sU + eloc * 136 + kb + q * 8) = o;
        }
    }
    __syncthreads();   // W-stage + t + sDst + sBnd ready

    // segment head flags: computed ONCE by wave 0 (uniform across columns)
    if (tid < 64) {
        int dprev = (tid == 0) ? sBnd[0] : sDst[tid - 1];
        unsigned long long m = __ballot(sDst[tid] != dprev);
        if (tid == 0) { sMask[0] = (unsigned)m; sMask[1] = (unsigned)(m >> 32); }
        if (tid == 63) sMask[2] = (sDst[63] != sBnd[1]) ? 1u : 0u;
    }

    // phase 2: MFMA. wave wv: rows (wv>>1)*16..+15, cols (wv&1)*64..+63
    short8 afr[4];
    {
        const ushort* ab = sU + (rh * 16 + l15) * 136 + quad * 8;
#pragma unroll
        for (int kc = 0; kc < 4; ++kc)
            afr[kc] = *(const short8*)(ab + kc * 32);
    }
    f32x4 acc[4];
#pragma unroll
    for (int ct = 0; ct < 4; ++ct) acc[ct] = (f32x4){0.f, 0.f, 0.f, 0.f};
#pragma unroll
    for (int kc = 0; kc < 4; ++kc) {
#pragma unroll
        for (int ct = 0; ct < 4; ++ct) {
            short8 bfr = *(const short8*)(sWT + ((ch * 4 + ct) * 16 + l15) * 136 + quad * 8 + kc * 32);
            acc[ct] = __builtin_amdgcn_mfma_f32_16x16x32_bf16(afr[kc], bfr, acc[ct], 0, 0, 0);
        }
    }
    __syncthreads();   // all t reads done -> sU reusable

    // epilogue: msgT[col][edge] bf16, stride 66 (odd dword stride -> conflict-free)
#pragma unroll
    for (int ct = 0; ct < 4; ++ct) {
        int col = (ch * 4 + ct) * 16 + l15;
        uint2 pr;
        pr.x = pk_bf16(acc[ct][0], acc[ct][1]);
        pr.y = pk_bf16(acc[ct][2], acc[ct][3]);
        *(uint2*)(sU + col * 66 + rh * 16 + quad * 4) = pr;
    }
    __syncthreads();

    // phase 3: mask-driven segmented max, 4 threads/col (16 edges each).
    {
        int j = tid & 127;
        int q4 = tid >> 7;            // 0..3 (wave-uniform)
        int base = q4 * 16;
        const ushort* mrow = sU + j * 66 + base;
        float vals[16];
#pragma unroll
        for (int q = 0; q < 4; ++q) {
            ushort4 mv = *(const ushort4*)(mrow + q * 4);
            vals[q * 4 + 0] = bf2f(mv.x);
            vals[q * 4 + 1] = bf2f(mv.y);
            vals[q * 4 + 2] = bf2f(mv.z);
            vals[q * 4 + 3] = bf2f(mv.w);
        }
        unsigned mlo = __builtin_amdgcn_readfirstlane(sMask[0]);
        unsigned mhi = __builtin_amdgcn_readfirstlane(sMask[1]);
        unsigned b64 = __builtin_amdgcn_readfirstlane(sMask[2]);
        unsigned long long mask = ((unsigned long long)mhi << 32) | mlo;
        unsigned slice = (unsigned)((mask >> base) & 0xFFFFull);
        unsigned nextbit = (q4 == 3) ? (b64 & 1u) : (unsigned)((mask >> (base + 16)) & 1ull);
        unsigned ext = slice | (nextbit << 16);
        bool contFrom = !(ext & 1u);
        float run = 0.f;
        bool first = true;
#pragma unroll
        for (int e3 = 0; e3 < 16; ++e3) {
            float vv2 = vals[e3];
            bool hb = (ext >> e3) & 1u;
            run = (e3 == 0 || hb) ? vv2 : fmaxf(run, vv2);
            bool end = (e3 == 15) || ((ext >> (e3 + 1)) & 1u);
            if (end) {
                int d = sDst[base + e3];
                unsigned en = encf(run);
                unsigned* ap = agg + (size_t)d * HID + j;
                bool useAtomic = (first && contFrom) || ((e3 == 15) && !nextbit);
                if (useAtomic) atomicMax(ap, en);
                else *ap = en;
                first = false;
            }
        }
    }
}

// ---- pooling with fused layer-2 combine: x2 never materialized; 16 slices/graph ----
__global__ __launch_bounds__(256) void pool_kernel(const ushort* __restrict__ x1,
                                                   const unsigned* __restrict__ agg2,
                                                   const float* __restrict__ b2b,
                                                   const int* __restrict__ cnt2,
                                                   const int* __restrict__ batch,
                                                   float* __restrict__ pooled) {
    int g = blockIdx.x >> 4, s = blockIdx.x & 15;
    int tid = threadIdx.x;
    int lo = 0, hi = N_NODES;
    while (lo < hi) { int mid = (lo + hi) >> 1; if (batch[mid] < g) lo = mid + 1; else hi = mid; }
    int start = lo;
    hi = N_NODES;
    while (lo < hi) { int mid = (lo + hi) >> 1; if (batch[mid] < g + 1) lo = mid + 1; else hi = mid; }
    int end = lo;
    int cnt = end - start;
    int b0 = start + (int)((long long)cnt * s / 16);
    int b1 = start + (int)((long long)cnt * (s + 1) / 16);
    if (b1 <= b0) return;
    int j = tid & 127;
    bool isx2 = tid >= 128;
    float bbj = isx2 ? b2b[j] : 0.f;
    float mx = -INFINITY, sm = 0.f;
    for (int n = b0; n < b1; ++n) {
        float xv = bf2f(x1[(size_t)n * HID + j]);
        float vv;
        if (isx2) {
            float a = 0.f;
            if (cnt2[n] > 0) a = decf(agg2[(size_t)n * HID + j]) + bbj;
            vv = fmaxf(a + xv, 0.f);
        } else {
            vv = xv;
        }
        mx = fmaxf(mx, vv);
        sm += vv;
    }
    atomicMax((unsigned*)pooled + (size_t)g * 512 + tid, encf(mx));
    atomicAdd(pooled + (size_t)g * 512 + 256 + tid, sm);
}

// ---- final MLP + log_softmax ----
__global__ __launch_bounds__(128) void final_kernel(const float* __restrict__ pooled,
                                                    const int* __restrict__ batch,
                                                    const float* __restrict__ Wf1,
                                                    const float* __restrict__ bf1,
                                                    const float* __restrict__ Wf2,
                                                    const float* __restrict__ bf2,
                                                    float* __restrict__ out) {
    __shared__ float sP[512];
    __shared__ float sH[128];
    int g = blockIdx.x, tid = threadIdx.x;
    int lo = 0, hi = N_NODES;
    while (lo < hi) { int mid = (lo + hi) >> 1; if (batch[mid] < g) lo = mid + 1; else hi = mid; }
    int start = lo;
    hi = N_NODES;
    while (lo < hi) { int mid = (lo + hi) >> 1; if (batch[mid] < g + 1) lo = mid + 1; else hi = mid; }
    int cnt = lo - start;
    float inv = 1.f / (float)(cnt > 1 ? cnt : 1);
#pragma unroll
    for (int q = 0; q < 4; ++q) {
        int idx = q * 128 + tid;
        float raw;
        if (idx < 256) {
            unsigned e = ((const unsigned*)pooled)[(size_t)g * 512 + idx];
            raw = (e == 0u) ? 0.f : decf(e);
        } else {
            raw = pooled[(size_t)g * 512 + idx] * inv;
        }
        sP[idx] = raw;
    }
    __syncthreads();
    float acc = bf1[tid];
    for (int k = 0; k < 512; ++k) acc = fmaf(sP[k], Wf1[k * HID + tid], acc);
    sH[tid] = fmaxf(acc, 0.f);
    __syncthreads();
    if (tid < 2) {
        float l = bf2[tid];
        for (int k = 0; k < 128; ++k) l = fmaf(sH[k], Wf2[k * 2 + tid], l);
        sP[tid] = l;
    }
    __syncthreads();
    if (tid == 0) {
        float l0 = sP[0], l1 = sP[1];
        float m = fmaxf(l0, l1);
        float ls = m + logf(expf(l0 - m) + expf(l1 - m));
        out[g * 2 + 0] = l0 - ls;
        out[g * 2 + 1] = l1 - ls;
    }
}

extern "C" void kernel_launch(void* const* d_in, const int* in_sizes, int n_in,
                              void* d_out, int out_size, void* d_ws, size_t ws_size,
                              hipStream_t stream) {
    const float* x     = (const float*)d_in[0];
    const float* W_enc = (const float*)d_in[1];
    const float* b_enc = (const float*)d_in[2];
    const float* W0    = (const float*)d_in[3];
    const float* b0    = (const float*)d_in[4];
    const float* W1a   = (const float*)d_in[5];
    const float* b1a   = (const float*)d_in[6];
    const float* W1b   = (const float*)d_in[7];
    const float* b1b   = (const float*)d_in[8];
    const float* W2a   = (const float*)d_in[9];
    const float* b2a   = (const float*)d_in[10];
    const float* W2b   = (const float*)d_in[11];
    const float* b2b   = (const float*)d_in[12];
    const float* Wf1   = (const float*)d_in[13];
    const float* bf1   = (const float*)d_in[14];
    const float* Wf2   = (const float*)d_in[15];
    const float* bf2   = (const float*)d_in[16];
    const int* src1    = (const int*)d_in[17];
    const int* dst1    = (const int*)d_in[18];
    const int* src2    = (const int*)d_in[19];
    const int* dst2    = (const int*)d_in[20];
    const int* batch   = (const int*)d_in[21];

    const size_t NB = (size_t)N_NODES * HID;     // 12.8M elements
    ushort* hbuf  = (ushort*)d_ws;               // h -> x1 (in place, bf16)
    unsigned* agg1 = (unsigned*)(hbuf + NB);     // layer-1 segment-max (u32 encoded)
    unsigned* agg2 = agg1 + NB;                  // layer-2 segment-max
    ushort* ubuf  = (ushort*)(agg2 + NB);        // u bf16
    ushort* vbuf  = ubuf + NB;                   // v bf16
    ushort* WT    = vbuf + NB;                   // 6 x 16384 bf16: Wb1,Wb2,Wu1,Wv1,Wu2,Wv2
    ushort* WbT1 = WT;
    ushort* WbT2 = WT + 1 * HID * HID;
    ushort* WuT1 = WT + 2 * HID * HID;
    ushort* WvT1 = WT + 3 * HID * HID;
    ushort* WuT2 = WT + 4 * HID * HID;
    ushort* WvT2 = WT + 5 * HID * HID;
    float* wkey  = (float*)(WT + 6 * HID * HID);
    float* bias0 = wkey + 128;
    float* xkey  = bias0 + 128;                  // dense per-node key (N_NODES fp32)
    float* pooled = xkey + N_NODES;              // 128*512 fp32
    int* cnt    = (int*)(pooled + 128 * 512);    // 2*N_NODES (both layers)
    int* cursor = cnt + 2 * N_NODES;             // 2*N_NODES
    int* partials = cursor + 2 * N_NODES;        // 1024
    int2* pedge = (int2*)(partials + 1024);      // 2*N_EDGES pairs (both layers)

    const int bothGrid = (2 * N_EDGES + 255) / 256;   // 3907
    const int edgeGrid = (N_EDGES + 63) / 64;         // 7813 windows of 64
    const int mmGrid   = (N_NODES + 127) / 128;       // 782
    const int zbGrid   = (2 * N_SEG + 3) / 4;         // 15626 (both layers, 16-edge granularity)
    const int prepGrid = 385 + SCAN1_B + 256;         // transpose+prep+zero(cnt,pooled)

    transp_prep_kernel<<<prepGrid, 256, 0, stream>>>(W1b, W2b, W1a, W2a, W_enc, b_enc, W0, b0,
                                                     WT, wkey, bias0, cnt, pooled);
    encode_kernel<<<N_NODES / 2, 256, 0, stream>>>(x, W0, wkey, bias0, hbuf, xkey);

    // ---- merged CSR build (both layers; cnt zeroed by transp_prep) ----
    hist_kernel<<<bothGrid, 256, 0, stream>>>(dst1, dst2, cnt);
    scan1_kernel<<<SCAN1_B, 256, 0, stream>>>(cnt, cursor, partials);
    scan2_kernel<<<1, 1024, 0, stream>>>(partials);
    scatter_kernel<<<bothGrid, 256, 0, stream>>>(src1, dst1, src2, dst2, cursor, partials, pedge);
    zbound_both_kernel<<<zbGrid, 256, 0, stream>>>(pedge, agg1, agg2);

    // ---- layer 1 ----
    mm_mfma_dual_kernel<<<mmGrid, 256, 0, stream>>>(hbuf, nullptr, nullptr, nullptr, nullptr,
                                                    WuT1, WvT1, b1a, ubuf, vbuf, N_NODES);
    edge_kernel<<<edgeGrid, 512, 0, stream>>>(ubuf, vbuf, xkey, pedge, WbT1, W1a + 256 * HID, agg1);

    // ---- layer 2 (mm fuses layer-1 combine; writes x1 to hbuf) ----
    mm_mfma_dual_kernel<<<mmGrid, 256, 0, stream>>>(hbuf, agg1, cnt, b1b, hbuf,
                                                    WuT2, WvT2, b2a, ubuf, vbuf, N_NODES);
    edge_kernel<<<edgeGrid, 512, 0, stream>>>(ubuf, vbuf, xkey, pedge + N_EDGES, WbT2, W2a + 256 * HID, agg2);

    // ---- pooling (layer-2 combine fused; pooled zeroed by transp_prep) + head ----
    pool_kernel<<<N_GRAPHS * 16, 256, 0, stream>>>(hbuf, agg2, b2b, cnt + N_NODES, batch, pooled);
    final_kernel<<<N_GRAPHS, 128, 0, stream>>>(pooled, batch, Wf1, bf1, Wf2, bf2, (float*)d_out);
}

// Round 8
// 590.423 us; speedup vs baseline: 1.1582x; 1.0522x over previous
//
#include <hip/hip_runtime.h>
#include <cstdint>

#define N_NODES 100000
#define N_EDGES 500000
#define N_GRAPHS 128
#define HID 128
#define SCAN1_B ((2 * N_NODES + 255) / 256)   // 782 blocks over concatenated counts
#define N_SEG (N_EDGES / 16)                  // 31250 16-edge segments per layer

typedef __attribute__((ext_vector_type(8))) short short8;
typedef __attribute__((ext_vector_type(4))) float f32x4;

// ---- monotone float<->uint encoding for max; enc==0 marks "never written" ----
__device__ __forceinline__ unsigned encf(float f) {
    unsigned u = __float_as_uint(f);
    return (u & 0x80000000u) ? ~u : (u | 0x80000000u);
}
__device__ __forceinline__ float decf(unsigned e) {
    unsigned u = (e & 0x80000000u) ? (e & 0x7FFFFFFFu) : ~e;
    return __uint_as_float(u);
}
__device__ __forceinline__ unsigned pk_bf16(float a, float b) {
    unsigned ua = __float_as_uint(a);
    unsigned ub = __float_as_uint(b);
    ua = (ua + 0x7fffu + ((ua >> 16) & 1u)) >> 16;
    ub = (ub + 0x7fffu + ((ub >> 16) & 1u)) & 0xffff0000u;
    return ua | ub;
}
__device__ __forceinline__ ushort bf16r(float f) {
    unsigned u = __float_as_uint(f);
    return (ushort)((u + 0x7fffu + ((u >> 16) & 1u)) >> 16);
}
__device__ __forceinline__ float bf2f(ushort h) {
    return __uint_as_float((unsigned)h << 16);
}

// ---- fused prep + encode:
//  blocks [0,384): transpose+convert weights -> bf16 [n][k]
//  blocks [384, 384+SCAN1_B): zero cnt
//  next 256 blocks: zero pooled
//  remaining 50000 blocks: encoder (wkey/bias0 recomputed inline, bit-identical
//  loop order to the old prep block, so results match exactly) ----
__global__ __launch_bounds__(256) void prep_encode_kernel(const float* __restrict__ W1b,
                                                          const float* __restrict__ W2b,
                                                          const float* __restrict__ W1a,
                                                          const float* __restrict__ W2a,
                                                          const float* __restrict__ W_enc,
                                                          const float* __restrict__ b_enc,
                                                          const float* __restrict__ W0,
                                                          const float* __restrict__ b0,
                                                          ushort* __restrict__ WT,
                                                          int* __restrict__ cnt,
                                                          float* __restrict__ pooled,
                                                          const float* __restrict__ x,
                                                          ushort* __restrict__ h,
                                                          float* __restrict__ xkey) {
    int blk = blockIdx.x;
    int tid = threadIdx.x;
    if (blk < 384) {   // weight transpose
        int m = blk >> 6;
        int i = (blk & 63) * 256 + tid;   // i = n*128 + k
        int n = i >> 7, k = i & 127;
        int src = k * HID + n;
        float v;
        switch (m) {
            case 0: v = W1b[src]; break;
            case 1: v = W2b[src]; break;
            case 2: v = W1a[src]; break;
            case 3: v = W1a[HID * HID + src] - W1a[src]; break;
            case 4: v = W2a[src]; break;
            default: v = W2a[HID * HID + src] - W2a[src]; break;
        }
        WT[m * HID * HID + i] = bf16r(v);
        return;
    }
    if (blk < 384 + SCAN1_B) {   // zero cnt
        int i = (blk - 384) * 256 + tid;
        if (i < 2 * N_NODES) cnt[i] = 0;
        return;
    }
    if (blk < 384 + SCAN1_B + 256) {   // zero pooled (exactly 128*512 floats)
        int i = (blk - 384 - SCAN1_B) * 256 + tid;
        pooled[i] = 0.f;
        return;
    }
    // encoder: 2 nodes per block
    int nb = blk - (384 + SCAN1_B + 256);
    int n = nb * 2 + (tid >> 7);
    int j = tid & 127;
    const float* xr = x + n * 16;
    float k0 = xr[0];
    if (j == 0) xkey[n] = k0;
    // inline wkey/bias0 (same expressions + loop order as the old prep block)
    float wk = 0.f, bk = b0[j];
    for (int k = 0; k < 32; ++k) {
        float w = W0[(15 + k) * HID + j];
        wk += W_enc[k] * w;
        bk += b_enc[k] * w;
    }
    float acc = bk + k0 * wk;
#pragma unroll
    for (int f = 0; f < 15; ++f)
        acc = fmaf(xr[1 + f], W0[f * HID + j], acc);
    h[n * HID + j] = bf16r(fmaxf(acc, 0.f));
}

// ---- dual MFMA (N x 128 bf16) @ (128 x 128) -> bf16, LDS-restaged epilogue ----
// v2: B-fragments were read from GLOBAL inside the MFMA loop — the exact
// anti-pattern R1 proved costs ~1.5x on edge_kernel. Now Wu is staged into
// LDS, pass u computed, Wv restaged over the same LDS, pass v computed.
// 512 threads / 8 waves (edge's proven shape); wave (rh,ch) owns rows
// rh*32..+31 x cols ch*64..+63. Arithmetic identical to v1.
__global__ __launch_bounds__(512, 4) void mm_mfma_dual_kernel(const ushort* __restrict__ in,
                                                              const unsigned* __restrict__ aggin,
                                                              const int* __restrict__ cntin,
                                                              const float* __restrict__ baddin,
                                                              ushort* __restrict__ xout,
                                                              const ushort* __restrict__ WuT,
                                                              const ushort* __restrict__ WvT,
                                                              const float* __restrict__ bv,
                                                              ushort* __restrict__ outu,
                                                              ushort* __restrict__ outv, int nrows) {
    __shared__ ushort sH[128 * 136];    // A-tile, then reused for D-restage
    __shared__ ushort sWT[128 * 136];   // Wu, then Wv
    int tid = threadIdx.x;
    int n0 = blockIdx.x * 128;
#pragma unroll
    for (int q = 0; q < 4; ++q) {
        int c = q * 512 + tid;
        int r = c >> 4, off = (c & 15) << 3;
        int n = n0 + r;
        uint4 vv = make_uint4(0, 0, 0, 0);
        if (n < nrows) {
            uint4 hv = *(const uint4*)(in + (size_t)n * HID + off);
            if (aggin) {
                float add[8];
#pragma unroll
                for (int p = 0; p < 8; ++p) add[p] = 0.f;
                if (cntin[n] > 0) {
                    uint4 e0 = *(const uint4*)(aggin + (size_t)n * HID + off);
                    uint4 e1 = *(const uint4*)(aggin + (size_t)n * HID + off + 4);
                    float4 bb0 = *(const float4*)(baddin + off);
                    float4 bb1 = *(const float4*)(baddin + off + 4);
                    add[0] = decf(e0.x) + bb0.x; add[1] = decf(e0.y) + bb0.y;
                    add[2] = decf(e0.z) + bb0.z; add[3] = decf(e0.w) + bb0.w;
                    add[4] = decf(e1.x) + bb1.x; add[5] = decf(e1.y) + bb1.y;
                    add[6] = decf(e1.z) + bb1.z; add[7] = decf(e1.w) + bb1.w;
                }
                unsigned hw[4] = {hv.x, hv.y, hv.z, hv.w};
                unsigned ow[4];
#pragma unroll
                for (int p = 0; p < 4; ++p) {
                    float lo = __uint_as_float(hw[p] << 16);
                    float hi = __uint_as_float(hw[p] & 0xffff0000u);
                    float r0 = fmaxf(add[2 * p] + lo, 0.f);
                    float r1 = fmaxf(add[2 * p + 1] + hi, 0.f);
                    ow[p] = pk_bf16(r0, r1);
                }
                vv = make_uint4(ow[0], ow[1], ow[2], ow[3]);
                *(uint4*)(xout + (size_t)n * HID + off) = vv;
            } else {
                vv = hv;
            }
        }
        *(uint4*)(sH + r * 136 + off) = vv;
    }
    // stage Wu
#pragma unroll
    for (int q = 0; q < 4; ++q) {
        int c = q * 512 + tid;
        int nn = c >> 4, off = (c & 15) << 3;
        *(uint4*)(sWT + nn * 136 + off) = *(const uint4*)(WuT + nn * 128 + off);
    }
    __syncthreads();

    int lane = tid & 63, wv = tid >> 6;
    int l15 = lane & 15, quad = lane >> 4;
    int ch = wv & 1, rh = wv >> 1;

    short8 afr[2][4];
#pragma unroll
    for (int rr = 0; rr < 2; ++rr) {
        const ushort* ab = sH + (rh * 32 + rr * 16 + l15) * 136 + quad * 8;
#pragma unroll
        for (int kc = 0; kc < 4; ++kc)
            afr[rr][kc] = *(const short8*)(ab + kc * 32);
    }

#pragma unroll
    for (int pass = 0; pass < 2; ++pass) {
        ushort* out = pass ? outv : outu;
        f32x4 acc[2][4];
#pragma unroll
        for (int rr = 0; rr < 2; ++rr)
#pragma unroll
            for (int ct = 0; ct < 4; ++ct) acc[rr][ct] = (f32x4){0.f, 0.f, 0.f, 0.f};
#pragma unroll
        for (int kc = 0; kc < 4; ++kc) {
#pragma unroll
            for (int ct = 0; ct < 4; ++ct) {
                short8 bfr = *(const short8*)(sWT + ((ch * 4 + ct) * 16 + l15) * 136 + quad * 8 + kc * 32);
                acc[0][ct] = __builtin_amdgcn_mfma_f32_16x16x32_bf16(afr[0][kc], bfr, acc[0][ct], 0, 0, 0);
                acc[1][ct] = __builtin_amdgcn_mfma_f32_16x16x32_bf16(afr[1][kc], bfr, acc[1][ct], 0, 0, 0);
            }
        }
        __syncthreads();   // sWT + sH(afr) reads done
#pragma unroll
        for (int ct = 0; ct < 4; ++ct) {
            int col = (ch * 4 + ct) * 16 + l15;
            float bb = pass ? bv[col] : 0.f;
#pragma unroll
            for (int rr = 0; rr < 2; ++rr) {
                int rowb = rh * 32 + rr * 16 + quad * 4;
#pragma unroll
                for (int reg = 0; reg < 4; ++reg)
                    sH[(rowb + reg) * 136 + col] = bf16r(acc[rr][ct][reg] + bb);
            }
        }
        if (pass == 0) {   // restage Wv over sWT (reads drained by the barrier above)
#pragma unroll
            for (int q = 0; q < 4; ++q) {
                int c = q * 512 + tid;
                int nn = c >> 4, off = (c & 15) << 3;
                *(uint4*)(sWT + nn * 136 + off) = *(const uint4*)(WvT + nn * 128 + off);
            }
        }
        __syncthreads();
#pragma unroll
        for (int q = 0; q < 4; ++q) {
            int c = q * 512 + tid;
            int r = c >> 4, off = (c & 15) << 3;
            int m = n0 + r;
            if (m < nrows)
                *(uint4*)(out + (size_t)m * HID + off) = *(const uint4*)(sH + r * 136 + off);
        }
    }
}

// ---- merged CSR build for BOTH layers ----
__global__ __launch_bounds__(256) void hist_kernel(const int* __restrict__ dst1,
                                                   const int* __restrict__ dst2,
                                                   int* __restrict__ cnt) {
    int e = blockIdx.x * 256 + threadIdx.x;
    if (e < N_EDGES) atomicAdd(&cnt[dst1[e]], 1);
    else if (e < 2 * N_EDGES) atomicAdd(&cnt[N_NODES + dst2[e - N_EDGES]], 1);
}

__global__ __launch_bounds__(256) void scan1_kernel(const int* __restrict__ cnt,
                                                    int* __restrict__ cursor,
                                                    int* __restrict__ partials) {
    __shared__ int tmp[256];
    int tid = threadIdx.x;
    int gid = blockIdx.x * 256 + tid;
    int v = (gid < 2 * N_NODES) ? cnt[gid] : 0;
    tmp[tid] = v;
    __syncthreads();
#pragma unroll
    for (int off = 1; off < 256; off <<= 1) {
        int t = (tid >= off) ? tmp[tid - off] : 0;
        __syncthreads();
        tmp[tid] += t;
        __syncthreads();
    }
    if (gid < 2 * N_NODES) cursor[gid] = tmp[tid] - v;   // local exclusive
    if (tid == 255) partials[blockIdx.x] = tmp[255];
}

__global__ __launch_bounds__(1024) void scan2_kernel(int* __restrict__ partials) {
    __shared__ int tmp[1024];
    int tid = threadIdx.x;
    int v = (tid < SCAN1_B) ? partials[tid] : 0;
    tmp[tid] = v;
    __syncthreads();
#pragma unroll
    for (int off = 1; off < 1024; off <<= 1) {
        int t = (tid >= off) ? tmp[tid - off] : 0;
        __syncthreads();
        tmp[tid] += t;
        __syncthreads();
    }
    if (tid < SCAN1_B) partials[tid] = tmp[tid] - v;  // exclusive
}

__global__ __launch_bounds__(256) void scatter_kernel(const int* __restrict__ src1,
                                                      const int* __restrict__ dst1,
                                                      const int* __restrict__ src2,
                                                      const int* __restrict__ dst2,
                                                      int* __restrict__ cursor,
                                                      const int* __restrict__ partials,
                                                      int2* __restrict__ pedge) {
    int e = blockIdx.x * 256 + threadIdx.x;
    if (e < N_EDGES) {
        int d = dst1[e];
        int pos = atomicAdd(&cursor[d], 1) + partials[d >> 8];
        pedge[pos] = make_int2(src1[e], d);
    } else if (e < 2 * N_EDGES) {
        int d = dst2[e - N_EDGES];
        int idx = N_NODES + d;
        int pos = atomicAdd(&cursor[idx], 1) + partials[idx >> 8];
        pedge[pos] = make_int2(src2[e - N_EDGES], d);   // pos lands in [N_EDGES, 2*N_EDGES)
    }
}

// ---- zero boundary agg rows for BOTH layers in one launch (u32 arrays).
//      16-edge granularity to match the phase-3 quarter size at window=64 ----
__global__ __launch_bounds__(256) void zbound_both_kernel(const int2* __restrict__ pedge,
                                                          unsigned* __restrict__ agg1,
                                                          unsigned* __restrict__ agg2) {
    int b = blockIdx.x * 4 + (threadIdx.x >> 6);
    int lane = threadIdx.x & 63;
    if (b >= 2 * N_SEG) return;
    int layer = b >= N_SEG;
    int bl = b - layer * N_SEG;
    const int2* pe = pedge + (size_t)layer * N_EDGES;
    unsigned* agg = layer ? agg2 : agg1;
    int d;
    if (bl == 0) {
        d = pe[N_EDGES - 1].y;               // tail row (clamped duplicates -> atomics)
    } else {
        int da = pe[bl * 16 - 1].y, db = pe[bl * 16].y;
        if (da != db) return;
        d = db;
    }
    *(uint2*)(agg + (size_t)d * HID + lane * 2) = make_uint2(0u, 0u);
}

// ---- edge conv: bf16 MFMA, 64-edge dst-sorted windows, 512 threads ----
// (R7's best shape, unchanged: non-persistent, LDS W-tile, ballot phase-3,
// dense xkey + wlast-in-registers.)
__global__ __launch_bounds__(512, 6) void edge_kernel(const ushort* __restrict__ u,
                                                      const ushort* __restrict__ v,
                                                      const float* __restrict__ xkey,
                                                      const int2* __restrict__ pedge,
                                                      const ushort* __restrict__ WbT,
                                                      const float* __restrict__ wlast,
                                                      unsigned* __restrict__ agg) {
    __shared__ ushort sWT[128 * 136];   // 34816 B: WbT[n][k] bf16, padded stride
    __shared__ ushort sU[64 * 136];     // 17408 B union: t[64][136] then msgT[128][66]
    __shared__ int sDst[64];
    __shared__ int sBnd[2];             // [0]=dst before window, [1]=dst after window
    __shared__ unsigned sMask[3];       // head-flag mask lo/hi + head64 flag
    int tid = threadIdx.x;
    int w0 = blockIdx.x * 64;

    // W stage: 2048 uint4 over 512 threads = 4 each (L2-hot 32KB)
#pragma unroll
    for (int q = 0; q < 4; ++q) {
        int c = q * 512 + tid;
        int n = c >> 4, off = (c & 15) << 3;
        *(uint4*)(sWT + n * 136 + off) = *(const uint4*)(WbT + n * 128 + off);
    }

    int eloc = tid >> 3;
    int sub = tid & 7;
    int kb = sub << 4;
    int lane = tid & 63, wv = tid >> 6;
    int l15 = lane & 15, quad = lane >> 4;
    int ch = wv & 1, rh = wv >> 1;

    // loop-invariant wlast slice for this thread's 16 columns -> registers
    float wreg[16];
    {
        const float4* wr4 = (const float4*)(wlast + kb);
#pragma unroll
        for (int q = 0; q < 4; ++q) {
            float4 wq = wr4[q];
            wreg[q * 4 + 0] = wq.x; wreg[q * 4 + 1] = wq.y;
            wreg[q * 4 + 2] = wq.z; wreg[q * 4 + 3] = wq.w;
        }
    }

    // phase 1: per-thread meta + gather + compute t
    {
        int e = w0 + eloc;
        if (e >= N_EDGES) e = N_EDGES - 1;   // clamp: idempotent under max
        int2 sd = pedge[e];
        if (sub == 0) sDst[eloc] = sd.y;
        if (tid < 2) {
            int eb = (tid == 0) ? (w0 - 1) : (w0 + 64);
            sBnd[tid] = (eb >= 0 && eb < N_EDGES) ? pedge[eb].y : -1;
        }
        float kd = xkey[sd.x] - xkey[sd.y];
        const uint4* ur = (const uint4*)(u + (size_t)sd.x * HID + kb);
        const uint4* vr = (const uint4*)(v + (size_t)sd.y * HID + kb);
        uint4 uu[2], vvv[2];
        uu[0] = ur[0]; uu[1] = ur[1];
        vvv[0] = vr[0]; vvv[1] = vr[1];
#pragma unroll
        for (int q = 0; q < 2; ++q) {
            unsigned pu[4] = {uu[q].x, uu[q].y, uu[q].z, uu[q].w};
            unsigned pv[4] = {vvv[q].x, vvv[q].y, vvv[q].z, vvv[q].w};
            unsigned pk[4];
#pragma unroll
            for (int p = 0; p < 4; ++p) {
                float a0 = __uint_as_float(pu[p] << 16) + __uint_as_float(pv[p] << 16);
                float a1 = __uint_as_float(pu[p] & 0xffff0000u) + __uint_as_float(pv[p] & 0xffff0000u);
                a0 = fmaf(kd, wreg[q * 8 + 2 * p], a0);
                a1 = fmaf(kd, wreg[q * 8 + 2 * p + 1], a1);
                a0 = fmaxf(a0, 0.1f * a0);   // leaky relu
                a1 = fmaxf(a1, 0.1f * a1);
                pk[p] = pk_bf16(a0, a1);
            }
            uint4 o; o.x = pk[0]; o.y = pk[1]; o.z = pk[2]; o.w = pk[3];
            *(uint4*)(sU + eloc * 136 + kb + q * 8) = o;
        }
    }
    __syncthreads();   // W-stage + t + sDst + sBnd ready

    // segment head flags: computed ONCE by wave 0 (uniform across columns)
    if (tid < 64) {
        int dprev = (tid == 0) ? sBnd[0] : sDst[tid - 1];
        unsigned long long m = __ballot(sDst[tid] != dprev);
        if (tid == 0) { sMask[0] = (unsigned)m; sMask[1] = (unsigned)(m >> 32); }
        if (tid == 63) sMask[2] = (sDst[63] != sBnd[1]) ? 1u : 0u;
    }

    // phase 2: MFMA. wave wv: rows (wv>>1)*16..+15, cols (wv&1)*64..+63
    short8 afr[4];
    {
        const ushort* ab = sU + (rh * 16 + l15) * 136 + quad * 8;
#pragma unroll
        for (int kc = 0; kc < 4; ++kc)
            afr[kc] = *(const short8*)(ab + kc * 32);
    }
    f32x4 acc[4];
#pragma unroll
    for (int ct = 0; ct < 4; ++ct) acc[ct] = (f32x4){0.f, 0.f, 0.f, 0.f};
#pragma unroll
    for (int kc = 0; kc < 4; ++kc) {
#pragma unroll
        for (int ct = 0; ct < 4; ++ct) {
            short8 bfr = *(const short8*)(sWT + ((ch * 4 + ct) * 16 + l15) * 136 + quad * 8 + kc * 32);
            acc[ct] = __builtin_amdgcn_mfma_f32_16x16x32_bf16(afr[kc], bfr, acc[ct], 0, 0, 0);
        }
    }
    __syncthreads();   // all t reads done -> sU reusable

    // epilogue: msgT[col][edge] bf16, stride 66 (odd dword stride -> conflict-free)
#pragma unroll
    for (int ct = 0; ct < 4; ++ct) {
        int col = (ch * 4 + ct) * 16 + l15;
        uint2 pr;
        pr.x = pk_bf16(acc[ct][0], acc[ct][1]);
        pr.y = pk_bf16(acc[ct][2], acc[ct][3]);
        *(uint2*)(sU + col * 66 + rh * 16 + quad * 4) = pr;
    }
    __syncthreads();

    // phase 3: mask-driven segmented max, 4 threads/col (16 edges each).
    {
        int j = tid & 127;
        int q4 = tid >> 7;            // 0..3 (wave-uniform)
        int base = q4 * 16;
        const ushort* mrow = sU + j * 66 + base;
        float vals[16];
#pragma unroll
        for (int q = 0; q < 4; ++q) {
            ushort4 mv = *(const ushort4*)(mrow + q * 4);
            vals[q * 4 + 0] = bf2f(mv.x);
            vals[q * 4 + 1] = bf2f(mv.y);
            vals[q * 4 + 2] = bf2f(mv.z);
            vals[q * 4 + 3] = bf2f(mv.w);
        }
        unsigned mlo = __builtin_amdgcn_readfirstlane(sMask[0]);
        unsigned mhi = __builtin_amdgcn_readfirstlane(sMask[1]);
        unsigned b64 = __builtin_amdgcn_readfirstlane(sMask[2]);
        unsigned long long mask = ((unsigned long long)mhi << 32) | mlo;
        unsigned slice = (unsigned)((mask >> base) & 0xFFFFull);
        unsigned nextbit = (q4 == 3) ? (b64 & 1u) : (unsigned)((mask >> (base + 16)) & 1ull);
        unsigned ext = slice | (nextbit << 16);
        bool contFrom = !(ext & 1u);
        float run = 0.f;
        bool first = true;
#pragma unroll
        for (int e3 = 0; e3 < 16; ++e3) {
            float vv2 = vals[e3];
            bool hb = (ext >> e3) & 1u;
            run = (e3 == 0 || hb) ? vv2 : fmaxf(run, vv2);
            bool end = (e3 == 15) || ((ext >> (e3 + 1)) & 1u);
            if (end) {
                int d = sDst[base + e3];
                unsigned en = encf(run);
                unsigned* ap = agg + (size_t)d * HID + j;
                bool useAtomic = (first && contFrom) || ((e3 == 15) && !nextbit);
                if (useAtomic) atomicMax(ap, en);
                else *ap = en;
                first = false;
            }
        }
    }
}

// ---- pooling with fused layer-2 combine: x2 never materialized; 16 slices/graph ----
__global__ __launch_bounds__(256) void pool_kernel(const ushort* __restrict__ x1,
                                                   const unsigned* __restrict__ agg2,
                                                   const float* __restrict__ b2b,
                                                   const int* __restrict__ cnt2,
                                                   const int* __restrict__ batch,
                                                   float* __restrict__ pooled) {
    int g = blockIdx.x >> 4, s = blockIdx.x & 15;
    int tid = threadIdx.x;
    int lo = 0, hi = N_NODES;
    while (lo < hi) { int mid = (lo + hi) >> 1; if (batch[mid] < g) lo = mid + 1; else hi = mid; }
    int start = lo;
    hi = N_NODES;
    while (lo < hi) { int mid = (lo + hi) >> 1; if (batch[mid] < g + 1) lo = mid + 1; else hi = mid; }
    int end = lo;
    int cnt = end - start;
    int b0 = start + (int)((long long)cnt * s / 16);
    int b1 = start + (int)((long long)cnt * (s + 1) / 16);
    if (b1 <= b0) return;
    int j = tid & 127;
    bool isx2 = tid >= 128;
    float bbj = isx2 ? b2b[j] : 0.f;
    float mx = -INFINITY, sm = 0.f;
    for (int n = b0; n < b1; ++n) {
        float xv = bf2f(x1[(size_t)n * HID + j]);
        float vv;
        if (isx2) {
            float a = 0.f;
            if (cnt2[n] > 0) a = decf(agg2[(size_t)n * HID + j]) + bbj;
            vv = fmaxf(a + xv, 0.f);
        } else {
            vv = xv;
        }
        mx = fmaxf(mx, vv);
        sm += vv;
    }
    atomicMax((unsigned*)pooled + (size_t)g * 512 + tid, encf(mx));
    atomicAdd(pooled + (size_t)g * 512 + 256 + tid, sm);
}

// ---- final MLP + log_softmax ----
__global__ __launch_bounds__(128) void final_kernel(const float* __restrict__ pooled,
                                                    const int* __restrict__ batch,
                                                    const float* __restrict__ Wf1,
                                                    const float* __restrict__ bf1,
                                                    const float* __restrict__ Wf2,
                                                    const float* __restrict__ bf2,
                                                    float* __restrict__ out) {
    __shared__ float sP[512];
    __shared__ float sH[128];
    int g = blockIdx.x, tid = threadIdx.x;
    int lo = 0, hi = N_NODES;
    while (lo < hi) { int mid = (lo + hi) >> 1; if (batch[mid] < g) lo = mid + 1; else hi = mid; }
    int start = lo;
    hi = N_NODES;
    while (lo < hi) { int mid = (lo + hi) >> 1; if (batch[mid] < g + 1) lo = mid + 1; else hi = mid; }
    int cnt = lo - start;
    float inv = 1.f / (float)(cnt > 1 ? cnt : 1);
#pragma unroll
    for (int q = 0; q < 4; ++q) {
        int idx = q * 128 + tid;
        float raw;
        if (idx < 256) {
            unsigned e = ((const unsigned*)pooled)[(size_t)g * 512 + idx];
            raw = (e == 0u) ? 0.f : decf(e);
        } else {
            raw = pooled[(size_t)g * 512 + idx] * inv;
        }
        sP[idx] = raw;
    }
    __syncthreads();
    float acc = bf1[tid];
    for (int k = 0; k < 512; ++k) acc = fmaf(sP[k], Wf1[k * HID + tid], acc);
    sH[tid] = fmaxf(acc, 0.f);
    __syncthreads();
    if (tid < 2) {
        float l = bf2[tid];
        for (int k = 0; k < 128; ++k) l = fmaf(sH[k], Wf2[k * 2 + tid], l);
        sP[tid] = l;
    }
    __syncthreads();
    if (tid == 0) {
        float l0 = sP[0], l1 = sP[1];
        float m = fmaxf(l0, l1);
        float ls = m + logf(expf(l0 - m) + expf(l1 - m));
        out[g * 2 + 0] = l0 - ls;
        out[g * 2 + 1] = l1 - ls;
    }
}

extern "C" void kernel_launch(void* const* d_in, const int* in_sizes, int n_in,
                              void* d_out, int out_size, void* d_ws, size_t ws_size,
                              hipStream_t stream) {
    const float* x     = (const float*)d_in[0];
    const float* W_enc = (const float*)d_in[1];
    const float* b_enc = (const float*)d_in[2];
    const float* W0    = (const float*)d_in[3];
    const float* b0    = (const float*)d_in[4];
    const float* W1a   = (const float*)d_in[5];
    const float* b1a   = (const float*)d_in[6];
    const float* W1b   = (const float*)d_in[7];
    const float* b1b   = (const float*)d_in[8];
    const float* W2a   = (const float*)d_in[9];
    const float* b2a   = (const float*)d_in[10];
    const float* W2b   = (const float*)d_in[11];
    const float* b2b   = (const float*)d_in[12];
    const float* Wf1   = (const float*)d_in[13];
    const float* bf1   = (const float*)d_in[14];
    const float* Wf2   = (const float*)d_in[15];
    const float* bf2   = (const float*)d_in[16];
    const int* src1    = (const int*)d_in[17];
    const int* dst1    = (const int*)d_in[18];
    const int* src2    = (const int*)d_in[19];
    const int* dst2    = (const int*)d_in[20];
    const int* batch   = (const int*)d_in[21];

    const size_t NB = (size_t)N_NODES * HID;     // 12.8M elements
    ushort* hbuf  = (ushort*)d_ws;               // h -> x1 (in place, bf16)
    unsigned* agg1 = (unsigned*)(hbuf + NB);     // layer-1 segment-max (u32 encoded)
    unsigned* agg2 = agg1 + NB;                  // layer-2 segment-max
    ushort* ubuf  = (ushort*)(agg2 + NB);        // u bf16
    ushort* vbuf  = ubuf + NB;                   // v bf16
    ushort* WT    = vbuf + NB;                   // 6 x 16384 bf16: Wb1,Wb2,Wu1,Wv1,Wu2,Wv2
    ushort* WbT1 = WT;
    ushort* WbT2 = WT + 1 * HID * HID;
    ushort* WuT1 = WT + 2 * HID * HID;
    ushort* WvT1 = WT + 3 * HID * HID;
    ushort* WuT2 = WT + 4 * HID * HID;
    ushort* WvT2 = WT + 5 * HID * HID;
    float* wkey  = (float*)(WT + 6 * HID * HID); // (slot kept; unused since R8)
    float* bias0 = wkey + 128;                   // (slot kept; unused since R8)
    float* xkey  = bias0 + 128;                  // dense per-node key (N_NODES fp32)
    float* pooled = xkey + N_NODES;              // 128*512 fp32
    int* cnt    = (int*)(pooled + 128 * 512);    // 2*N_NODES (both layers)
    int* cursor = cnt + 2 * N_NODES;             // 2*N_NODES
    int* partials = cursor + 2 * N_NODES;        // 1024
    int2* pedge = (int2*)(partials + 1024);      // 2*N_EDGES pairs (both layers)

    const int bothGrid = (2 * N_EDGES + 255) / 256;   // 3907
    const int edgeGrid = (N_EDGES + 63) / 64;         // 7813 windows of 64
    const int mmGrid   = (N_NODES + 127) / 128;       // 782
    const int zbGrid   = (2 * N_SEG + 3) / 4;         // 15626 (both layers, 16-edge granularity)
    const int prepGrid = 384 + SCAN1_B + 256 + N_NODES / 2;   // transpose+zero+encode

    prep_encode_kernel<<<prepGrid, 256, 0, stream>>>(W1b, W2b, W1a, W2a, W_enc, b_enc, W0, b0,
                                                     WT, cnt, pooled, x, hbuf, xkey);

    // ---- merged CSR build (both layers; cnt zeroed by prep_encode) ----
    hist_kernel<<<bothGrid, 256, 0, stream>>>(dst1, dst2, cnt);
    scan1_kernel<<<SCAN1_B, 256, 0, stream>>>(cnt, cursor, partials);
    scan2_kernel<<<1, 1024, 0, stream>>>(partials);
    scatter_kernel<<<bothGrid, 256, 0, stream>>>(src1, dst1, src2, dst2, cursor, partials, pedge);
    zbound_both_kernel<<<zbGrid, 256, 0, stream>>>(pedge, agg1, agg2);

    // ---- layer 1 ----
    mm_mfma_dual_kernel<<<mmGrid, 512, 0, stream>>>(hbuf, nullptr, nullptr, nullptr, nullptr,
                                                    WuT1, WvT1, b1a, ubuf, vbuf, N_NODES);
    edge_kernel<<<edgeGrid, 512, 0, stream>>>(ubuf, vbuf, xkey, pedge, WbT1, W1a + 256 * HID, agg1);

    // ---- layer 2 (mm fuses layer-1 combine; writes x1 to hbuf) ----
    mm_mfma_dual_kernel<<<mmGrid, 512, 0, stream>>>(hbuf, agg1, cnt, b1b, hbuf,
                                                    WuT2, WvT2, b2a, ubuf, vbuf, N_NODES);
    edge_kernel<<<edgeGrid, 512, 0, stream>>>(ubuf, vbuf, xkey, pedge + N_EDGES, WbT2, W2a + 256 * HID, agg2);

    // ---- pooling (layer-2 combine fused; pooled zeroed by prep_encode) + head ----
    pool_kernel<<<N_GRAPHS * 16, 256, 0, stream>>>(hbuf, agg2, b2b, cnt + N_NODES, batch, pooled);
    final_kernel<<<N_GRAPHS, 128, 0, stream>>>(pooled, batch, Wf1, bf1, Wf2, bf2, (float*)d_out);
}

// Round 9
// 551.389 us; speedup vs baseline: 1.2402x; 1.0708x over previous
//
#include <hip/hip_runtime.h>
#include <cstdint>

#define N_NODES 100000
#define N_EDGES 500000
#define N_GRAPHS 128
#define HID 128
#define SCAN1_B ((2 * N_NODES + 255) / 256)   // 782 blocks over concatenated counts
#define N_SEG (N_EDGES / 16)                  // 31250 16-edge segments per layer

typedef __attribute__((ext_vector_type(8))) short short8;
typedef __attribute__((ext_vector_type(4))) float f32x4;

// ---- monotone float<->uint encoding for max; enc==0 marks "never written" ----
__device__ __forceinline__ unsigned encf(float f) {
    unsigned u = __float_as_uint(f);
    return (u & 0x80000000u) ? ~u : (u | 0x80000000u);
}
__device__ __forceinline__ float decf(unsigned e) {
    unsigned u = (e & 0x80000000u) ? (e & 0x7FFFFFFFu) : ~e;
    return __uint_as_float(u);
}
__device__ __forceinline__ unsigned pk_bf16(float a, float b) {
    unsigned ua = __float_as_uint(a);
    unsigned ub = __float_as_uint(b);
    ua = (ua + 0x7fffu + ((ua >> 16) & 1u)) >> 16;
    ub = (ub + 0x7fffu + ((ub >> 16) & 1u)) & 0xffff0000u;
    return ua | ub;
}
__device__ __forceinline__ ushort bf16r(float f) {
    unsigned u = __float_as_uint(f);
    return (ushort)((u + 0x7fffu + ((u >> 16) & 1u)) >> 16);
}
__device__ __forceinline__ float bf2f(ushort h) {
    return __uint_as_float((unsigned)h << 16);
}

// ---- transpose+convert weights -> bf16 [n][k]; block 384 computes wkey/bias0
//      ONCE (R8's per-thread inline recompute was a 32-deep serial load chain
//      x 12.8M threads = 105 us — the top dispatch); blocks >=385 zero
//      cnt + pooled ----
__global__ __launch_bounds__(256) void transp_prep_kernel(const float* __restrict__ W1b,
                                                          const float* __restrict__ W2b,
                                                          const float* __restrict__ W1a,
                                                          const float* __restrict__ W2a,
                                                          const float* __restrict__ W_enc,
                                                          const float* __restrict__ b_enc,
                                                          const float* __restrict__ W0,
                                                          const float* __restrict__ b0,
                                                          ushort* __restrict__ WT,
                                                          float* __restrict__ wkey,
                                                          float* __restrict__ bias0,
                                                          int* __restrict__ cnt,
                                                          float* __restrict__ pooled) {
    int blk = blockIdx.x;
    int tid = threadIdx.x;
    if (blk >= 385) {   // zeroing duty: 782 blocks for cnt, 256 for pooled
        int z = blk - 385;
        if (z < SCAN1_B) {
            int i = z * 256 + tid;
            if (i < 2 * N_NODES) cnt[i] = 0;
        } else {
            int i = (z - SCAN1_B) * 256 + tid;   // exactly 128*512 = 65536 floats
            pooled[i] = 0.f;
        }
        return;
    }
    if (blk == 384) {   // prep
        if (tid < HID) {
            float wk = 0.f, bk = b0[tid];
            for (int k = 0; k < 32; ++k) {
                float w = W0[(15 + k) * HID + tid];
                wk += W_enc[k] * w;
                bk += b_enc[k] * w;
            }
            wkey[tid] = wk;
            bias0[tid] = bk;
        }
        return;
    }
    int m = blk >> 6;
    int i = (blk & 63) * 256 + tid;   // i = n*128 + k
    int n = i >> 7, k = i & 127;
    int src = k * HID + n;
    float v;
    switch (m) {
        case 0: v = W1b[src]; break;
        case 1: v = W2b[src]; break;
        case 2: v = W1a[src]; break;
        case 3: v = W1a[HID * HID + src] - W1a[src]; break;
        case 4: v = W2a[src]; break;
        default: v = W2a[HID * HID + src] - W2a[src]; break;
    }
    WT[m * HID * HID + i] = bf16r(v);
}

// ---- encoder: h = relu(features @ W0[0:15] + key*wkey + bias0) -> bf16;
//      also emits dense xkey[n] = x[n*16] for the edge kernels ----
__global__ __launch_bounds__(256) void encode_kernel(const float* __restrict__ x,
                                                     const float* __restrict__ W0,
                                                     const float* __restrict__ wkey,
                                                     const float* __restrict__ bias0,
                                                     ushort* __restrict__ h,
                                                     float* __restrict__ xkey) {
    int n = blockIdx.x * 2 + (threadIdx.x >> 7);
    int j = threadIdx.x & 127;
    const float* xr = x + n * 16;
    float k0 = xr[0];
    if (j == 0) xkey[n] = k0;
    float acc = bias0[j] + k0 * wkey[j];
#pragma unroll
    for (int f = 0; f < 15; ++f)
        acc = fmaf(xr[1 + f], W0[f * HID + j], acc);
    h[n * HID + j] = bf16r(fmaxf(acc, 0.f));
}

// ---- dual MFMA (N x 128 bf16) @ (128 x 128) -> bf16, LDS-restaged epilogue ----
// R8: Wu staged into LDS, pass u computed, Wv restaged over the same LDS,
// pass v computed. 512 threads / 8 waves; wave (rh,ch) owns rows rh*32..+31
// x cols ch*64..+63. (Global-B inside the MFMA loop was the R1 anti-pattern;
// this fix was worth ~105 us across the two mm dispatches.)
__global__ __launch_bounds__(512, 4) void mm_mfma_dual_kernel(const ushort* __restrict__ in,
                                                              const unsigned* __restrict__ aggin,
                                                              const int* __restrict__ cntin,
                                                              const float* __restrict__ baddin,
                                                              ushort* __restrict__ xout,
                                                              const ushort* __restrict__ WuT,
                                                              const ushort* __restrict__ WvT,
                                                              const float* __restrict__ bv,
                                                              ushort* __restrict__ outu,
                                                              ushort* __restrict__ outv, int nrows) {
    __shared__ ushort sH[128 * 136];    // A-tile, then reused for D-restage
    __shared__ ushort sWT[128 * 136];   // Wu, then Wv
    int tid = threadIdx.x;
    int n0 = blockIdx.x * 128;
#pragma unroll
    for (int q = 0; q < 4; ++q) {
        int c = q * 512 + tid;
        int r = c >> 4, off = (c & 15) << 3;
        int n = n0 + r;
        uint4 vv = make_uint4(0, 0, 0, 0);
        if (n < nrows) {
            uint4 hv = *(const uint4*)(in + (size_t)n * HID + off);
            if (aggin) {
                float add[8];
#pragma unroll
                for (int p = 0; p < 8; ++p) add[p] = 0.f;
                if (cntin[n] > 0) {
                    uint4 e0 = *(const uint4*)(aggin + (size_t)n * HID + off);
                    uint4 e1 = *(const uint4*)(aggin + (size_t)n * HID + off + 4);
                    float4 bb0 = *(const float4*)(baddin + off);
                    float4 bb1 = *(const float4*)(baddin + off + 4);
                    add[0] = decf(e0.x) + bb0.x; add[1] = decf(e0.y) + bb0.y;
                    add[2] = decf(e0.z) + bb0.z; add[3] = decf(e0.w) + bb0.w;
                    add[4] = decf(e1.x) + bb1.x; add[5] = decf(e1.y) + bb1.y;
                    add[6] = decf(e1.z) + bb1.z; add[7] = decf(e1.w) + bb1.w;
                }
                unsigned hw[4] = {hv.x, hv.y, hv.z, hv.w};
                unsigned ow[4];
#pragma unroll
                for (int p = 0; p < 4; ++p) {
                    float lo = __uint_as_float(hw[p] << 16);
                    float hi = __uint_as_float(hw[p] & 0xffff0000u);
                    float r0 = fmaxf(add[2 * p] + lo, 0.f);
                    float r1 = fmaxf(add[2 * p + 1] + hi, 0.f);
                    ow[p] = pk_bf16(r0, r1);
                }
                vv = make_uint4(ow[0], ow[1], ow[2], ow[3]);
                *(uint4*)(xout + (size_t)n * HID + off) = vv;
            } else {
                vv = hv;
            }
        }
        *(uint4*)(sH + r * 136 + off) = vv;
    }
    // stage Wu
#pragma unroll
    for (int q = 0; q < 4; ++q) {
        int c = q * 512 + tid;
        int nn = c >> 4, off = (c & 15) << 3;
        *(uint4*)(sWT + nn * 136 + off) = *(const uint4*)(WuT + nn * 128 + off);
    }
    __syncthreads();

    int lane = tid & 63, wv = tid >> 6;
    int l15 = lane & 15, quad = lane >> 4;
    int ch = wv & 1, rh = wv >> 1;

    short8 afr[2][4];
#pragma unroll
    for (int rr = 0; rr < 2; ++rr) {
        const ushort* ab = sH + (rh * 32 + rr * 16 + l15) * 136 + quad * 8;
#pragma unroll
        for (int kc = 0; kc < 4; ++kc)
            afr[rr][kc] = *(const short8*)(ab + kc * 32);
    }

#pragma unroll
    for (int pass = 0; pass < 2; ++pass) {
        ushort* out = pass ? outv : outu;
        f32x4 acc[2][4];
#pragma unroll
        for (int rr = 0; rr < 2; ++rr)
#pragma unroll
            for (int ct = 0; ct < 4; ++ct) acc[rr][ct] = (f32x4){0.f, 0.f, 0.f, 0.f};
#pragma unroll
        for (int kc = 0; kc < 4; ++kc) {
#pragma unroll
            for (int ct = 0; ct < 4; ++ct) {
                short8 bfr = *(const short8*)(sWT + ((ch * 4 + ct) * 16 + l15) * 136 + quad * 8 + kc * 32);
                acc[0][ct] = __builtin_amdgcn_mfma_f32_16x16x32_bf16(afr[0][kc], bfr, acc[0][ct], 0, 0, 0);
                acc[1][ct] = __builtin_amdgcn_mfma_f32_16x16x32_bf16(afr[1][kc], bfr, acc[1][ct], 0, 0, 0);
            }
        }
        __syncthreads();   // sWT + sH(afr) reads done
#pragma unroll
        for (int ct = 0; ct < 4; ++ct) {
            int col = (ch * 4 + ct) * 16 + l15;
            float bb = pass ? bv[col] : 0.f;
#pragma unroll
            for (int rr = 0; rr < 2; ++rr) {
                int rowb = rh * 32 + rr * 16 + quad * 4;
#pragma unroll
                for (int reg = 0; reg < 4; ++reg)
                    sH[(rowb + reg) * 136 + col] = bf16r(acc[rr][ct][reg] + bb);
            }
        }
        if (pass == 0) {   // restage Wv over sWT (reads drained by the barrier above)
#pragma unroll
            for (int q = 0; q < 4; ++q) {
                int c = q * 512 + tid;
                int nn = c >> 4, off = (c & 15) << 3;
                *(uint4*)(sWT + nn * 136 + off) = *(const uint4*)(WvT + nn * 128 + off);
            }
        }
        __syncthreads();
#pragma unroll
        for (int q = 0; q < 4; ++q) {
            int c = q * 512 + tid;
            int r = c >> 4, off = (c & 15) << 3;
            int m = n0 + r;
            if (m < nrows)
                *(uint4*)(out + (size_t)m * HID + off) = *(const uint4*)(sH + r * 136 + off);
        }
    }
}

// ---- merged CSR build for BOTH layers ----
__global__ __launch_bounds__(256) void hist_kernel(const int* __restrict__ dst1,
                                                   const int* __restrict__ dst2,
                                                   int* __restrict__ cnt) {
    int e = blockIdx.x * 256 + threadIdx.x;
    if (e < N_EDGES) atomicAdd(&cnt[dst1[e]], 1);
    else if (e < 2 * N_EDGES) atomicAdd(&cnt[N_NODES + dst2[e - N_EDGES]], 1);
}

__global__ __launch_bounds__(256) void scan1_kernel(const int* __restrict__ cnt,
                                                    int* __restrict__ cursor,
                                                    int* __restrict__ partials) {
    __shared__ int tmp[256];
    int tid = threadIdx.x;
    int gid = blockIdx.x * 256 + tid;
    int v = (gid < 2 * N_NODES) ? cnt[gid] : 0;
    tmp[tid] = v;
    __syncthreads();
#pragma unroll
    for (int off = 1; off < 256; off <<= 1) {
        int t = (tid >= off) ? tmp[tid - off] : 0;
        __syncthreads();
        tmp[tid] += t;
        __syncthreads();
    }
    if (gid < 2 * N_NODES) cursor[gid] = tmp[tid] - v;   // local exclusive
    if (tid == 255) partials[blockIdx.x] = tmp[255];
}

__global__ __launch_bounds__(1024) void scan2_kernel(int* __restrict__ partials) {
    __shared__ int tmp[1024];
    int tid = threadIdx.x;
    int v = (tid < SCAN1_B) ? partials[tid] : 0;
    tmp[tid] = v;
    __syncthreads();
#pragma unroll
    for (int off = 1; off < 1024; off <<= 1) {
        int t = (tid >= off) ? tmp[tid - off] : 0;
        __syncthreads();
        tmp[tid] += t;
        __syncthreads();
    }
    if (tid < SCAN1_B) partials[tid] = tmp[tid] - v;  // exclusive
}

__global__ __launch_bounds__(256) void scatter_kernel(const int* __restrict__ src1,
                                                      const int* __restrict__ dst1,
                                                      const int* __restrict__ src2,
                                                      const int* __restrict__ dst2,
                                                      int* __restrict__ cursor,
                                                      const int* __restrict__ partials,
                                                      int2* __restrict__ pedge) {
    int e = blockIdx.x * 256 + threadIdx.x;
    if (e < N_EDGES) {
        int d = dst1[e];
        int pos = atomicAdd(&cursor[d], 1) + partials[d >> 8];
        pedge[pos] = make_int2(src1[e], d);
    } else if (e < 2 * N_EDGES) {
        int d = dst2[e - N_EDGES];
        int idx = N_NODES + d;
        int pos = atomicAdd(&cursor[idx], 1) + partials[idx >> 8];
        pedge[pos] = make_int2(src2[e - N_EDGES], d);   // pos lands in [N_EDGES, 2*N_EDGES)
    }
}

// ---- zero boundary agg rows for BOTH layers in one launch (u32 arrays).
//      16-edge granularity to match the phase-3 quarter size at window=64 ----
__global__ __launch_bounds__(256) void zbound_both_kernel(const int2* __restrict__ pedge,
                                                          unsigned* __restrict__ agg1,
                                                          unsigned* __restrict__ agg2) {
    int b = blockIdx.x * 4 + (threadIdx.x >> 6);
    int lane = threadIdx.x & 63;
    if (b >= 2 * N_SEG) return;
    int layer = b >= N_SEG;
    int bl = b - layer * N_SEG;
    const int2* pe = pedge + (size_t)layer * N_EDGES;
    unsigned* agg = layer ? agg2 : agg1;
    int d;
    if (bl == 0) {
        d = pe[N_EDGES - 1].y;               // tail row (clamped duplicates -> atomics)
    } else {
        int da = pe[bl * 16 - 1].y, db = pe[bl * 16].y;
        if (da != db) return;
        d = db;
    }
    *(uint2*)(agg + (size_t)d * HID + lane * 2) = make_uint2(0u, 0u);
}

// ---- edge conv: bf16 MFMA, 64-edge dst-sorted windows, 512 threads ----
// (R7's best shape, unchanged: non-persistent, LDS W-tile, ballot phase-3,
// dense xkey + wlast-in-registers. Pinned at ~91.5 us across 8 structural
// variants — treated as at its structural limit.)
__global__ __launch_bounds__(512, 6) void edge_kernel(const ushort* __restrict__ u,
                                                      const ushort* __restrict__ v,
                                                      const float* __restrict__ xkey,
                                                      const int2* __restrict__ pedge,
                                                      const ushort* __restrict__ WbT,
                                                      const float* __restrict__ wlast,
                                                      unsigned* __restrict__ agg) {
    __shared__ ushort sWT[128 * 136];   // 34816 B: WbT[n][k] bf16, padded stride
    __shared__ ushort sU[64 * 136];     // 17408 B union: t[64][136] then msgT[128][66]
    __shared__ int sDst[64];
    __shared__ int sBnd[2];             // [0]=dst before window, [1]=dst after window
    __shared__ unsigned sMask[3];       // head-flag mask lo/hi + head64 flag
    int tid = threadIdx.x;
    int w0 = blockIdx.x * 64;

    // W stage: 2048 uint4 over 512 threads = 4 each (L2-hot 32KB)
#pragma unroll
    for (int q = 0; q < 4; ++q) {
        int c = q * 512 + tid;
        int n = c >> 4, off = (c & 15) << 3;
        *(uint4*)(sWT + n * 136 + off) = *(const uint4*)(WbT + n * 128 + off);
    }

    int eloc = tid >> 3;
    int sub = tid & 7;
    int kb = sub << 4;
    int lane = tid & 63, wv = tid >> 6;
    int l15 = lane & 15, quad = lane >> 4;
    int ch = wv & 1, rh = wv >> 1;

    // loop-invariant wlast slice for this thread's 16 columns -> registers
    float wreg[16];
    {
        const float4* wr4 = (const float4*)(wlast + kb);
#pragma unroll
        for (int q = 0; q < 4; ++q) {
            float4 wq = wr4[q];
            wreg[q * 4 + 0] = wq.x; wreg[q * 4 + 1] = wq.y;
            wreg[q * 4 + 2] = wq.z; wreg[q * 4 + 3] = wq.w;
        }
    }

    // phase 1: per-thread meta + gather + compute t
    {
        int e = w0 + eloc;
        if (e >= N_EDGES) e = N_EDGES - 1;   // clamp: idempotent under max
        int2 sd = pedge[e];
        if (sub == 0) sDst[eloc] = sd.y;
        if (tid < 2) {
            int eb = (tid == 0) ? (w0 - 1) : (w0 + 64);
            sBnd[tid] = (eb >= 0 && eb < N_EDGES) ? pedge[eb].y : -1;
        }
        float kd = xkey[sd.x] - xkey[sd.y];
        const uint4* ur = (const uint4*)(u + (size_t)sd.x * HID + kb);
        const uint4* vr = (const uint4*)(v + (size_t)sd.y * HID + kb);
        uint4 uu[2], vvv[2];
        uu[0] = ur[0]; uu[1] = ur[1];
        vvv[0] = vr[0]; vvv[1] = vr[1];
#pragma unroll
        for (int q = 0; q < 2; ++q) {
            unsigned pu[4] = {uu[q].x, uu[q].y, uu[q].z, uu[q].w};
            unsigned pv[4] = {vvv[q].x, vvv[q].y, vvv[q].z, vvv[q].w};
            unsigned pk[4];
#pragma unroll
            for (int p = 0; p < 4; ++p) {
                float a0 = __uint_as_float(pu[p] << 16) + __uint_as_float(pv[p] << 16);
                float a1 = __uint_as_float(pu[p] & 0xffff0000u) + __uint_as_float(pv[p] & 0xffff0000u);
                a0 = fmaf(kd, wreg[q * 8 + 2 * p], a0);
                a1 = fmaf(kd, wreg[q * 8 + 2 * p + 1], a1);
                a0 = fmaxf(a0, 0.1f * a0);   // leaky relu
                a1 = fmaxf(a1, 0.1f * a1);
                pk[p] = pk_bf16(a0, a1);
            }
            uint4 o; o.x = pk[0]; o.y = pk[1]; o.z = pk[2]; o.w = pk[3];
            *(uint4*)(sU + eloc * 136 + kb + q * 8) = o;
        }
    }
    __syncthreads();   // W-stage + t + sDst + sBnd ready

    // segment head flags: computed ONCE by wave 0 (uniform across columns)
    if (tid < 64) {
        int dprev = (tid == 0) ? sBnd[0] : sDst[tid - 1];
        unsigned long long m = __ballot(sDst[tid] != dprev);
        if (tid == 0) { sMask[0] = (unsigned)m; sMask[1] = (unsigned)(m >> 32); }
        if (tid == 63) sMask[2] = (sDst[63] != sBnd[1]) ? 1u : 0u;
    }

    // phase 2: MFMA. wave wv: rows (wv>>1)*16..+15, cols (wv&1)*64..+63
    short8 afr[4];
    {
        const ushort* ab = sU + (rh * 16 + l15) * 136 + quad * 8;
#pragma unroll
        for (int kc = 0; kc < 4; ++kc)
            afr[kc] = *(const short8*)(ab + kc * 32);
    }
    f32x4 acc[4];
#pragma unroll
    for (int ct = 0; ct < 4; ++ct) acc[ct] = (f32x4){0.f, 0.f, 0.f, 0.f};
#pragma unroll
    for (int kc = 0; kc < 4; ++kc) {
#pragma unroll
        for (int ct = 0; ct < 4; ++ct) {
            short8 bfr = *(const short8*)(sWT + ((ch * 4 + ct) * 16 + l15) * 136 + quad * 8 + kc * 32);
            acc[ct] = __builtin_amdgcn_mfma_f32_16x16x32_bf16(afr[kc], bfr, acc[ct], 0, 0, 0);
        }
    }
    __syncthreads();   // all t reads done -> sU reusable

    // epilogue: msgT[col][edge] bf16, stride 66 (odd dword stride -> conflict-free)
#pragma unroll
    for (int ct = 0; ct < 4; ++ct) {
        int col = (ch * 4 + ct) * 16 + l15;
        uint2 pr;
        pr.x = pk_bf16(acc[ct][0], acc[ct][1]);
        pr.y = pk_bf16(acc[ct][2], acc[ct][3]);
        *(uint2*)(sU + col * 66 + rh * 16 + quad * 4) = pr;
    }
    __syncthreads();

    // phase 3: mask-driven segmented max, 4 threads/col (16 edges each).
    {
        int j = tid & 127;
        int q4 = tid >> 7;            // 0..3 (wave-uniform)
        int base = q4 * 16;
        const ushort* mrow = sU + j * 66 + base;
        float vals[16];
#pragma unroll
        for (int q = 0; q < 4; ++q) {
            ushort4 mv = *(const ushort4*)(mrow + q * 4);
            vals[q * 4 + 0] = bf2f(mv.x);
            vals[q * 4 + 1] = bf2f(mv.y);
            vals[q * 4 + 2] = bf2f(mv.z);
            vals[q * 4 + 3] = bf2f(mv.w);
        }
        unsigned mlo = __builtin_amdgcn_readfirstlane(sMask[0]);
        unsigned mhi = __builtin_amdgcn_readfirstlane(sMask[1]);
        unsigned b64 = __builtin_amdgcn_readfirstlane(sMask[2]);
        unsigned long long mask = ((unsigned long long)mhi << 32) | mlo;
        unsigned slice = (unsigned)((mask >> base) & 0xFFFFull);
        unsigned nextbit = (q4 == 3) ? (b64 & 1u) : (unsigned)((mask >> (base + 16)) & 1ull);
        unsigned ext = slice | (nextbit << 16);
        bool contFrom = !(ext & 1u);
        float run = 0.f;
        bool first = true;
#pragma unroll
        for (int e3 = 0; e3 < 16; ++e3) {
            float vv2 = vals[e3];
            bool hb = (ext >> e3) & 1u;
            run = (e3 == 0 || hb) ? vv2 : fmaxf(run, vv2);
            bool end = (e3 == 15) || ((ext >> (e3 + 1)) & 1u);
            if (end) {
                int d = sDst[base + e3];
                unsigned en = encf(run);
                unsigned* ap = agg + (size_t)d * HID + j;
                bool useAtomic = (first && contFrom) || ((e3 == 15) && !nextbit);
                if (useAtomic) atomicMax(ap, en);
                else *ap = en;
                first = false;
            }
        }
    }
}

// ---- pooling with fused layer-2 combine: x2 never materialized; 16 slices/graph ----
__global__ __launch_bounds__(256) void pool_kernel(const ushort* __restrict__ x1,
                                                   const unsigned* __restrict__ agg2,
                                                   const float* __restrict__ b2b,
                                                   const int* __restrict__ cnt2,
                                                   const int* __restrict__ batch,
                                                   float* __restrict__ pooled) {
    int g = blockIdx.x >> 4, s = blockIdx.x & 15;
    int tid = threadIdx.x;
    int lo = 0, hi = N_NODES;
    while (lo < hi) { int mid = (lo + hi) >> 1; if (batch[mid] < g) lo = mid + 1; else hi = mid; }
    int start = lo;
    hi = N_NODES;
    while (lo < hi) { int mid = (lo + hi) >> 1; if (batch[mid] < g + 1) lo = mid + 1; else hi = mid; }
    int end = lo;
    int cnt = end - start;
    int b0 = start + (int)((long long)cnt * s / 16);
    int b1 = start + (int)((long long)cnt * (s + 1) / 16);
    if (b1 <= b0) return;
    int j = tid & 127;
    bool isx2 = tid >= 128;
    float bbj = isx2 ? b2b[j] : 0.f;
    float mx = -INFINITY, sm = 0.f;
    for (int n = b0; n < b1; ++n) {
        float xv = bf2f(x1[(size_t)n * HID + j]);
        float vv;
        if (isx2) {
            float a = 0.f;
            if (cnt2[n] > 0) a = decf(agg2[(size_t)n * HID + j]) + bbj;
            vv = fmaxf(a + xv, 0.f);
        } else {
            vv = xv;
        }
        mx = fmaxf(mx, vv);
        sm += vv;
    }
    atomicMax((unsigned*)pooled + (size_t)g * 512 + tid, encf(mx));
    atomicAdd(pooled + (size_t)g * 512 + 256 + tid, sm);
}

// ---- final MLP + log_softmax ----
__global__ __launch_bounds__(128) void final_kernel(const float* __restrict__ pooled,
                                                    const int* __restrict__ batch,
                                                    const float* __restrict__ Wf1,
                                                    const float* __restrict__ bf1,
                                                    const float* __restrict__ Wf2,
                                                    const float* __restrict__ bf2,
                                                    float* __restrict__ out) {
    __shared__ float sP[512];
    __shared__ float sH[128];
    int g = blockIdx.x, tid = threadIdx.x;
    int lo = 0, hi = N_NODES;
    while (lo < hi) { int mid = (lo + hi) >> 1; if (batch[mid] < g) lo = mid + 1; else hi = mid; }
    int start = lo;
    hi = N_NODES;
    while (lo < hi) { int mid = (lo + hi) >> 1; if (batch[mid] < g + 1) lo = mid + 1; else hi = mid; }
    int cnt = lo - start;
    float inv = 1.f / (float)(cnt > 1 ? cnt : 1);
#pragma unroll
    for (int q = 0; q < 4; ++q) {
        int idx = q * 128 + tid;
        float raw;
        if (idx < 256) {
            unsigned e = ((const unsigned*)pooled)[(size_t)g * 512 + idx];
            raw = (e == 0u) ? 0.f : decf(e);
        } else {
            raw = pooled[(size_t)g * 512 + idx] * inv;
        }
        sP[idx] = raw;
    }
    __syncthreads();
    float acc = bf1[tid];
    for (int k = 0; k < 512; ++k) acc = fmaf(sP[k], Wf1[k * HID + tid], acc);
    sH[tid] = fmaxf(acc, 0.f);
    __syncthreads();
    if (tid < 2) {
        float l = bf2[tid];
        for (int k = 0; k < 128; ++k) l = fmaf(sH[k], Wf2[k * 2 + tid], l);
        sP[tid] = l;
    }
    __syncthreads();
    if (tid == 0) {
        float l0 = sP[0], l1 = sP[1];
        float m = fmaxf(l0, l1);
        float ls = m + logf(expf(l0 - m) + expf(l1 - m));
        out[g * 2 + 0] = l0 - ls;
        out[g * 2 + 1] = l1 - ls;
    }
}

extern "C" void kernel_launch(void* const* d_in, const int* in_sizes, int n_in,
                              void* d_out, int out_size, void* d_ws, size_t ws_size,
                              hipStream_t stream) {
    const float* x     = (const float*)d_in[0];
    const float* W_enc = (const float*)d_in[1];
    const float* b_enc = (const float*)d_in[2];
    const float* W0    = (const float*)d_in[3];
    const float* b0    = (const float*)d_in[4];
    const float* W1a   = (const float*)d_in[5];
    const float* b1a   = (const float*)d_in[6];
    const float* W1b   = (const float*)d_in[7];
    const float* b1b   = (const float*)d_in[8];
    const float* W2a   = (const float*)d_in[9];
    const float* b2a   = (const float*)d_in[10];
    const float* W2b   = (const float*)d_in[11];
    const float* b2b   = (const float*)d_in[12];
    const float* Wf1   = (const float*)d_in[13];
    const float* bf1   = (const float*)d_in[14];
    const float* Wf2   = (const float*)d_in[15];
    const float* bf2   = (const float*)d_in[16];
    const int* src1    = (const int*)d_in[17];
    const int* dst1    = (const int*)d_in[18];
    const int* src2    = (const int*)d_in[19];
    const int* dst2    = (const int*)d_in[20];
    const int* batch   = (const int*)d_in[21];

    const size_t NB = (size_t)N_NODES * HID;     // 12.8M elements
    ushort* hbuf  = (ushort*)d_ws;               // h -> x1 (in place, bf16)
    unsigned* agg1 = (unsigned*)(hbuf + NB);     // layer-1 segment-max (u32 encoded)
    unsigned* agg2 = agg1 + NB;                  // layer-2 segment-max
    ushort* ubuf  = (ushort*)(agg2 + NB);        // u bf16
    ushort* vbuf  = ubuf + NB;                   // v bf16
    ushort* WT    = vbuf + NB;                   // 6 x 16384 bf16: Wb1,Wb2,Wu1,Wv1,Wu2,Wv2
    ushort* WbT1 = WT;
    ushort* WbT2 = WT + 1 * HID * HID;
    ushort* WuT1 = WT + 2 * HID * HID;
    ushort* WvT1 = WT + 3 * HID * HID;
    ushort* WuT2 = WT + 4 * HID * HID;
    ushort* WvT2 = WT + 5 * HID * HID;
    float* wkey  = (float*)(WT + 6 * HID * HID);
    float* bias0 = wkey + 128;
    float* xkey  = bias0 + 128;                  // dense per-node key (N_NODES fp32)
    float* pooled = xkey + N_NODES;              // 128*512 fp32
    int* cnt    = (int*)(pooled + 128 * 512);    // 2*N_NODES (both layers)
    int* cursor = cnt + 2 * N_NODES;             // 2*N_NODES
    int* partials = cursor + 2 * N_NODES;        // 1024
    int2* pedge = (int2*)(partials + 1024);      // 2*N_EDGES pairs (both layers)

    const int bothGrid = (2 * N_EDGES + 255) / 256;   // 3907
    const int edgeGrid = (N_EDGES + 63) / 64;         // 7813 windows of 64
    const int mmGrid   = (N_NODES + 127) / 128;       // 782
    const int zbGrid   = (2 * N_SEG + 3) / 4;         // 15626 (both layers, 16-edge granularity)
    const int prepGrid = 385 + SCAN1_B + 256;         // transpose+prep+zero(cnt,pooled)

    transp_prep_kernel<<<prepGrid, 256, 0, stream>>>(W1b, W2b, W1a, W2a, W_enc, b_enc, W0, b0,
                                                     WT, wkey, bias0, cnt, pooled);
    encode_kernel<<<N_NODES / 2, 256, 0, stream>>>(x, W0, wkey, bias0, hbuf, xkey);

    // ---- merged CSR build (both layers; cnt zeroed by transp_prep) ----
    hist_kernel<<<bothGrid, 256, 0, stream>>>(dst1, dst2, cnt);
    scan1_kernel<<<SCAN1_B, 256, 0, stream>>>(cnt, cursor, partials);
    scan2_kernel<<<1, 1024, 0, stream>>>(partials);
    scatter_kernel<<<bothGrid, 256, 0, stream>>>(src1, dst1, src2, dst2, cursor, partials, pedge);
    zbound_both_kernel<<<zbGrid, 256, 0, stream>>>(pedge, agg1, agg2);

    // ---- layer 1 ----
    mm_mfma_dual_kernel<<<mmGrid, 512, 0, stream>>>(hbuf, nullptr, nullptr, nullptr, nullptr,
                                                    WuT1, WvT1, b1a, ubuf, vbuf, N_NODES);
    edge_kernel<<<edgeGrid, 512, 0, stream>>>(ubuf, vbuf, xkey, pedge, WbT1, W1a + 256 * HID, agg1);

    // ---- layer 2 (mm fuses layer-1 combine; writes x1 to hbuf) ----
    mm_mfma_dual_kernel<<<mmGrid, 512, 0, stream>>>(hbuf, agg1, cnt, b1b, hbuf,
                                                    WuT2, WvT2, b2a, ubuf, vbuf, N_NODES);
    edge_kernel<<<edgeGrid, 512, 0, stream>>>(ubuf, vbuf, xkey, pedge + N_EDGES, WbT2, W2a + 256 * HID, agg2);

    // ---- pooling (layer-2 combine fused; pooled zeroed by transp_prep) + head ----
    pool_kernel<<<N_GRAPHS * 16, 256, 0, stream>>>(hbuf, agg2, b2b, cnt + N_NODES, batch, pooled);
    final_kernel<<<N_GRAPHS, 128, 0, stream>>>(pooled, batch, Wf1, bf1, Wf2, bf2, (float*)d_out);
}

// Round 10
// 492.537 us; speedup vs baseline: 1.3884x; 1.1195x over previous
//
#include <hip/hip_runtime.h>
#include <cstdint>

#define N_NODES 100000
#define N_EDGES 500000
#define N_GRAPHS 128
#define HID 128
#define SCAN1_B ((2 * N_NODES + 255) / 256)   // 782 blocks over concatenated counts
#define BOTH_GRID ((2 * N_EDGES + 255) / 256) // 3907 blocks over concatenated edges

typedef __attribute__((ext_vector_type(8))) short short8;
typedef __attribute__((ext_vector_type(4))) float f32x4;

// ---- monotone float<->uint encoding for max; enc==0 marks "never written" ----
__device__ __forceinline__ unsigned encf(float f) {
    unsigned u = __float_as_uint(f);
    return (u & 0x80000000u) ? ~u : (u | 0x80000000u);
}
__device__ __forceinline__ float decf(unsigned e) {
    unsigned u = (e & 0x80000000u) ? (e & 0x7FFFFFFFu) : ~e;
    return __uint_as_float(u);
}
__device__ __forceinline__ unsigned pk_bf16(float a, float b) {
    unsigned ua = __float_as_uint(a);
    unsigned ub = __float_as_uint(b);
    ua = (ua + 0x7fffu + ((ua >> 16) & 1u)) >> 16;
    ub = (ub + 0x7fffu + ((ub >> 16) & 1u)) & 0xffff0000u;
    return ua | ub;
}
__device__ __forceinline__ ushort bf16r(float f) {
    unsigned u = __float_as_uint(f);
    return (ushort)((u + 0x7fffu + ((u >> 16) & 1u)) >> 16);
}
__device__ __forceinline__ float bf2f(ushort h) {
    return __uint_as_float((unsigned)h << 16);
}

// ---- transpose+convert weights -> bf16 [n][k]; block 384 computes wkey/bias0
//      ONCE; blocks >=385 zero cnt + pooled ----
__global__ __launch_bounds__(256) void transp_prep_kernel(const float* __restrict__ W1b,
                                                          const float* __restrict__ W2b,
                                                          const float* __restrict__ W1a,
                                                          const float* __restrict__ W2a,
                                                          const float* __restrict__ W_enc,
                                                          const float* __restrict__ b_enc,
                                                          const float* __restrict__ W0,
                                                          const float* __restrict__ b0,
                                                          ushort* __restrict__ WT,
                                                          float* __restrict__ wkey,
                                                          float* __restrict__ bias0,
                                                          int* __restrict__ cnt,
                                                          float* __restrict__ pooled) {
    int blk = blockIdx.x;
    int tid = threadIdx.x;
    if (blk >= 385) {   // zeroing duty: 782 blocks for cnt, 256 for pooled
        int z = blk - 385;
        if (z < SCAN1_B) {
            int i = z * 256 + tid;
            if (i < 2 * N_NODES) cnt[i] = 0;
        } else {
            int i = (z - SCAN1_B) * 256 + tid;   // exactly 128*512 = 65536 floats
            pooled[i] = 0.f;
        }
        return;
    }
    if (blk == 384) {   // prep
        if (tid < HID) {
            float wk = 0.f, bk = b0[tid];
            for (int k = 0; k < 32; ++k) {
                float w = W0[(15 + k) * HID + tid];
                wk += W_enc[k] * w;
                bk += b_enc[k] * w;
            }
            wkey[tid] = wk;
            bias0[tid] = bk;
        }
        return;
    }
    int m = blk >> 6;
    int i = (blk & 63) * 256 + tid;   // i = n*128 + k
    int n = i >> 7, k = i & 127;
    int src = k * HID + n;
    float v;
    switch (m) {
        case 0: v = W1b[src]; break;
        case 1: v = W2b[src]; break;
        case 2: v = W1a[src]; break;
        case 3: v = W1a[HID * HID + src] - W1a[src]; break;
        case 4: v = W2a[src]; break;
        default: v = W2a[HID * HID + src] - W2a[src]; break;
    }
    WT[m * HID * HID + i] = bf16r(v);
}

// ---- fused encoder + histogram: hist's 1M random atomics (latency-bound,
//      VALU 0.5%) overlap encode's compute. atomicAdd's return value IS the
//      within-dst sequence number -> stored to seq[], which makes the later
//      scatter atomic-free. ----
__global__ __launch_bounds__(256) void encode_hist_kernel(const float* __restrict__ x,
                                                          const float* __restrict__ W0,
                                                          const float* __restrict__ wkey,
                                                          const float* __restrict__ bias0,
                                                          ushort* __restrict__ h,
                                                          float* __restrict__ xkey,
                                                          const int* __restrict__ dst1,
                                                          const int* __restrict__ dst2,
                                                          int* __restrict__ cnt,
                                                          int* __restrict__ seq) {
    int blk = blockIdx.x;
    int tid = threadIdx.x;
    if (blk < BOTH_GRID) {   // hist + seq for both layers
        int e = blk * 256 + tid;
        if (e < N_EDGES) seq[e] = atomicAdd(&cnt[dst1[e]], 1);
        else if (e < 2 * N_EDGES) seq[e] = atomicAdd(&cnt[N_NODES + dst2[e - N_EDGES]], 1);
        return;
    }
    int nb = blk - BOTH_GRID;
    int n = nb * 2 + (tid >> 7);
    int j = tid & 127;
    const float* xr = x + n * 16;
    float k0 = xr[0];
    if (j == 0) xkey[n] = k0;
    float acc = bias0[j] + k0 * wkey[j];
#pragma unroll
    for (int f = 0; f < 15; ++f)
        acc = fmaf(xr[1 + f], W0[f * HID + j], acc);
    h[n * HID + j] = bf16r(fmaxf(acc, 0.f));
}

// ---- dual MFMA (N x 128 bf16) @ (128 x 128) -> bf16, LDS-restaged epilogue ----
__global__ __launch_bounds__(512, 4) void mm_mfma_dual_kernel(const ushort* __restrict__ in,
                                                              const unsigned* __restrict__ aggin,
                                                              const int* __restrict__ cntin,
                                                              const float* __restrict__ baddin,
                                                              ushort* __restrict__ xout,
                                                              const ushort* __restrict__ WuT,
                                                              const ushort* __restrict__ WvT,
                                                              const float* __restrict__ bv,
                                                              ushort* __restrict__ outu,
                                                              ushort* __restrict__ outv, int nrows) {
    __shared__ ushort sH[128 * 136];    // A-tile, then reused for D-restage
    __shared__ ushort sWT[128 * 136];   // Wu, then Wv
    int tid = threadIdx.x;
    int n0 = blockIdx.x * 128;
#pragma unroll
    for (int q = 0; q < 4; ++q) {
        int c = q * 512 + tid;
        int r = c >> 4, off = (c & 15) << 3;
        int n = n0 + r;
        uint4 vv = make_uint4(0, 0, 0, 0);
        if (n < nrows) {
            uint4 hv = *(const uint4*)(in + (size_t)n * HID + off);
            if (aggin) {
                float add[8];
#pragma unroll
                for (int p = 0; p < 8; ++p) add[p] = 0.f;
                if (cntin[n] > 0) {
                    uint4 e0 = *(const uint4*)(aggin + (size_t)n * HID + off);
                    uint4 e1 = *(const uint4*)(aggin + (size_t)n * HID + off + 4);
                    float4 bb0 = *(const float4*)(baddin + off);
                    float4 bb1 = *(const float4*)(baddin + off + 4);
                    add[0] = decf(e0.x) + bb0.x; add[1] = decf(e0.y) + bb0.y;
                    add[2] = decf(e0.z) + bb0.z; add[3] = decf(e0.w) + bb0.w;
                    add[4] = decf(e1.x) + bb1.x; add[5] = decf(e1.y) + bb1.y;
                    add[6] = decf(e1.z) + bb1.z; add[7] = decf(e1.w) + bb1.w;
                }
                unsigned hw[4] = {hv.x, hv.y, hv.z, hv.w};
                unsigned ow[4];
#pragma unroll
                for (int p = 0; p < 4; ++p) {
                    float lo = __uint_as_float(hw[p] << 16);
                    float hi = __uint_as_float(hw[p] & 0xffff0000u);
                    float r0 = fmaxf(add[2 * p] + lo, 0.f);
                    float r1 = fmaxf(add[2 * p + 1] + hi, 0.f);
                    ow[p] = pk_bf16(r0, r1);
                }
                vv = make_uint4(ow[0], ow[1], ow[2], ow[3]);
                *(uint4*)(xout + (size_t)n * HID + off) = vv;
            } else {
                vv = hv;
            }
        }
        *(uint4*)(sH + r * 136 + off) = vv;
    }
    // stage Wu
#pragma unroll
    for (int q = 0; q < 4; ++q) {
        int c = q * 512 + tid;
        int nn = c >> 4, off = (c & 15) << 3;
        *(uint4*)(sWT + nn * 136 + off) = *(const uint4*)(WuT + nn * 128 + off);
    }
    __syncthreads();

    int lane = tid & 63, wv = tid >> 6;
    int l15 = lane & 15, quad = lane >> 4;
    int ch = wv & 1, rh = wv >> 1;

    short8 afr[2][4];
#pragma unroll
    for (int rr = 0; rr < 2; ++rr) {
        const ushort* ab = sH + (rh * 32 + rr * 16 + l15) * 136 + quad * 8;
#pragma unroll
        for (int kc = 0; kc < 4; ++kc)
            afr[rr][kc] = *(const short8*)(ab + kc * 32);
    }

#pragma unroll
    for (int pass = 0; pass < 2; ++pass) {
        ushort* out = pass ? outv : outu;
        f32x4 acc[2][4];
#pragma unroll
        for (int rr = 0; rr < 2; ++rr)
#pragma unroll
            for (int ct = 0; ct < 4; ++ct) acc[rr][ct] = (f32x4){0.f, 0.f, 0.f, 0.f};
#pragma unroll
        for (int kc = 0; kc < 4; ++kc) {
#pragma unroll
            for (int ct = 0; ct < 4; ++ct) {
                short8 bfr = *(const short8*)(sWT + ((ch * 4 + ct) * 16 + l15) * 136 + quad * 8 + kc * 32);
                acc[0][ct] = __builtin_amdgcn_mfma_f32_16x16x32_bf16(afr[0][kc], bfr, acc[0][ct], 0, 0, 0);
                acc[1][ct] = __builtin_amdgcn_mfma_f32_16x16x32_bf16(afr[1][kc], bfr, acc[1][ct], 0, 0, 0);
            }
        }
        __syncthreads();   // sWT + sH(afr) reads done
#pragma unroll
        for (int ct = 0; ct < 4; ++ct) {
            int col = (ch * 4 + ct) * 16 + l15;
            float bb = pass ? bv[col] : 0.f;
#pragma unroll
            for (int rr = 0; rr < 2; ++rr) {
                int rowb = rh * 32 + rr * 16 + quad * 4;
#pragma unroll
                for (int reg = 0; reg < 4; ++reg)
                    sH[(rowb + reg) * 136 + col] = bf16r(acc[rr][ct][reg] + bb);
            }
        }
        if (pass == 0) {   // restage Wv over sWT (reads drained by the barrier above)
#pragma unroll
            for (int q = 0; q < 4; ++q) {
                int c = q * 512 + tid;
                int nn = c >> 4, off = (c & 15) << 3;
                *(uint4*)(sWT + nn * 136 + off) = *(const uint4*)(WvT + nn * 128 + off);
            }
        }
        __syncthreads();
#pragma unroll
        for (int q = 0; q < 4; ++q) {
            int c = q * 512 + tid;
            int r = c >> 4, off = (c & 15) << 3;
            int m = n0 + r;
            if (m < nrows)
                *(uint4*)(out + (size_t)m * HID + off) = *(const uint4*)(sH + r * 136 + off);
        }
    }
}

__global__ __launch_bounds__(256) void scan1_kernel(const int* __restrict__ cnt,
                                                    int* __restrict__ cursor,
                                                    int* __restrict__ partials) {
    __shared__ int tmp[256];
    int tid = threadIdx.x;
    int gid = blockIdx.x * 256 + tid;
    int v = (gid < 2 * N_NODES) ? cnt[gid] : 0;
    tmp[tid] = v;
    __syncthreads();
#pragma unroll
    for (int off = 1; off < 256; off <<= 1) {
        int t = (tid >= off) ? tmp[tid - off] : 0;
        __syncthreads();
        tmp[tid] += t;
        __syncthreads();
    }
    if (gid < 2 * N_NODES) cursor[gid] = tmp[tid] - v;   // local exclusive
    if (tid == 255) partials[blockIdx.x] = tmp[255];
}

__global__ __launch_bounds__(1024) void scan2_kernel(int* __restrict__ partials) {
    __shared__ int tmp[1024];
    int tid = threadIdx.x;
    int v = (tid < SCAN1_B) ? partials[tid] : 0;
    tmp[tid] = v;
    __syncthreads();
#pragma unroll
    for (int off = 1; off < 1024; off <<= 1) {
        int t = (tid >= off) ? tmp[tid - off] : 0;
        __syncthreads();
        tmp[tid] += t;
        __syncthreads();
    }
    if (tid < SCAN1_B) partials[tid] = tmp[tid] - v;  // exclusive
}

// ---- fused CSR finalize: atomic-free. Part A (one thread/node): densely
//      EXPAND the sorted dst array from counts+offsets, and zero boundary agg
//      rows node-centrically (row spans a 16-edge boundary, or owns a layer's
//      last edge — provably equivalent to the old pairwise-boundary test since
//      N_EDGES%16==0). Part B (one thread/edge): scatter src via
//      pos = offset[dst] + seq[e]; seq came free from hist's atomicAdd. ----
__global__ __launch_bounds__(256) void build_kernel(const int* __restrict__ src1,
                                                    const int* __restrict__ dst1,
                                                    const int* __restrict__ src2,
                                                    const int* __restrict__ dst2,
                                                    const int* __restrict__ cnt,
                                                    const int* __restrict__ cursor,
                                                    const int* __restrict__ partials,
                                                    const int* __restrict__ seq,
                                                    int* __restrict__ srcS,
                                                    int* __restrict__ dstS,
                                                    unsigned* __restrict__ agg1,
                                                    unsigned* __restrict__ agg2) {
    int blk = blockIdx.x;
    int tid = threadIdx.x;
    if (blk < SCAN1_B) {   // part A: expand dst + zero boundary rows
        int gid = blk * 256 + tid;
        if (gid >= 2 * N_NODES) return;
        int c = cnt[gid];
        if (c == 0) return;
        int o = cursor[gid] + partials[gid >> 8];
        int layer = gid >= N_NODES;
        int d = gid - layer * N_NODES;
        for (int i = 0; i < c; ++i) dstS[o + i] = d;
        bool spans = (o >> 4) != ((o + c - 1) >> 4);
        bool tail = (o + c == N_EDGES) || (o + c == 2 * N_EDGES);
        if (spans || tail) {
            unsigned* agg = layer ? agg2 : agg1;
            uint4* ap = (uint4*)(agg + (size_t)d * HID);
#pragma unroll
            for (int i = 0; i < 32; ++i) ap[i] = make_uint4(0u, 0u, 0u, 0u);
        }
        return;
    }
    int e = (blk - SCAN1_B) * 256 + tid;
    int s, idx;
    if (e < N_EDGES) { s = src1[e]; idx = dst1[e]; }
    else if (e < 2 * N_EDGES) { s = src2[e - N_EDGES]; idx = N_NODES + dst2[e - N_EDGES]; }
    else return;
    int pos = cursor[idx] + partials[idx >> 8] + seq[e];
    srcS[pos] = s;
}

// ---- edge conv: bf16 MFMA, 64-edge dst-sorted windows, 512 threads ----
// (R7 shape; src/dst now split arrays — dst generated densely, src scattered.)
__global__ __launch_bounds__(512, 6) void edge_kernel(const ushort* __restrict__ u,
                                                      const ushort* __restrict__ v,
                                                      const float* __restrict__ xkey,
                                                      const int* __restrict__ srcS,
                                                      const int* __restrict__ dstS,
                                                      const ushort* __restrict__ WbT,
                                                      const float* __restrict__ wlast,
                                                      unsigned* __restrict__ agg) {
    __shared__ ushort sWT[128 * 136];   // 34816 B: WbT[n][k] bf16, padded stride
    __shared__ ushort sU[64 * 136];     // 17408 B union: t[64][136] then msgT[128][66]
    __shared__ int sDst[64];
    __shared__ int sBnd[2];             // [0]=dst before window, [1]=dst after window
    __shared__ unsigned sMask[3];       // head-flag mask lo/hi + head64 flag
    int tid = threadIdx.x;
    int w0 = blockIdx.x * 64;

    // W stage: 2048 uint4 over 512 threads = 4 each (L2-hot 32KB)
#pragma unroll
    for (int q = 0; q < 4; ++q) {
        int c = q * 512 + tid;
        int n = c >> 4, off = (c & 15) << 3;
        *(uint4*)(sWT + n * 136 + off) = *(const uint4*)(WbT + n * 128 + off);
    }

    int eloc = tid >> 3;
    int sub = tid & 7;
    int kb = sub << 4;
    int lane = tid & 63, wv = tid >> 6;
    int l15 = lane & 15, quad = lane >> 4;
    int ch = wv & 1, rh = wv >> 1;

    // loop-invariant wlast slice for this thread's 16 columns -> registers
    float wreg[16];
    {
        const float4* wr4 = (const float4*)(wlast + kb);
#pragma unroll
        for (int q = 0; q < 4; ++q) {
            float4 wq = wr4[q];
            wreg[q * 4 + 0] = wq.x; wreg[q * 4 + 1] = wq.y;
            wreg[q * 4 + 2] = wq.z; wreg[q * 4 + 3] = wq.w;
        }
    }

    // phase 1: per-thread meta + gather + compute t
    {
        int e = w0 + eloc;
        if (e >= N_EDGES) e = N_EDGES - 1;   // clamp: idempotent under max
        int sx = srcS[e], sy = dstS[e];
        if (sub == 0) sDst[eloc] = sy;
        if (tid < 2) {
            int eb = (tid == 0) ? (w0 - 1) : (w0 + 64);
            sBnd[tid] = (eb >= 0 && eb < N_EDGES) ? dstS[eb] : -1;
        }
        float kd = xkey[sx] - xkey[sy];
        const uint4* ur = (const uint4*)(u + (size_t)sx * HID + kb);
        const uint4* vr = (const uint4*)(v + (size_t)sy * HID + kb);
        uint4 uu[2], vvv[2];
        uu[0] = ur[0]; uu[1] = ur[1];
        vvv[0] = vr[0]; vvv[1] = vr[1];
#pragma unroll
        for (int q = 0; q < 2; ++q) {
            unsigned pu[4] = {uu[q].x, uu[q].y, uu[q].z, uu[q].w};
            unsigned pv[4] = {vvv[q].x, vvv[q].y, vvv[q].z, vvv[q].w};
            unsigned pk[4];
#pragma unroll
            for (int p = 0; p < 4; ++p) {
                float a0 = __uint_as_float(pu[p] << 16) + __uint_as_float(pv[p] << 16);
                float a1 = __uint_as_float(pu[p] & 0xffff0000u) + __uint_as_float(pv[p] & 0xffff0000u);
                a0 = fmaf(kd, wreg[q * 8 + 2 * p], a0);
                a1 = fmaf(kd, wreg[q * 8 + 2 * p + 1], a1);
                a0 = fmaxf(a0, 0.1f * a0);   // leaky relu
                a1 = fmaxf(a1, 0.1f * a1);
                pk[p] = pk_bf16(a0, a1);
            }
            uint4 o; o.x = pk[0]; o.y = pk[1]; o.z = pk[2]; o.w = pk[3];
            *(uint4*)(sU + eloc * 136 + kb + q * 8) = o;
        }
    }
    __syncthreads();   // W-stage + t + sDst + sBnd ready

    // segment head flags: computed ONCE by wave 0 (uniform across columns)
    if (tid < 64) {
        int dprev = (tid == 0) ? sBnd[0] : sDst[tid - 1];
        unsigned long long m = __ballot(sDst[tid] != dprev);
        if (tid == 0) { sMask[0] = (unsigned)m; sMask[1] = (unsigned)(m >> 32); }
        if (tid == 63) sMask[2] = (sDst[63] != sBnd[1]) ? 1u : 0u;
    }

    // phase 2: MFMA. wave wv: rows (wv>>1)*16..+15, cols (wv&1)*64..+63
    short8 afr[4];
    {
        const ushort* ab = sU + (rh * 16 + l15) * 136 + quad * 8;
#pragma unroll
        for (int kc = 0; kc < 4; ++kc)
            afr[kc] = *(const short8*)(ab + kc * 32);
    }
    f32x4 acc[4];
#pragma unroll
    for (int ct = 0; ct < 4; ++ct) acc[ct] = (f32x4){0.f, 0.f, 0.f, 0.f};
#pragma unroll
    for (int kc = 0; kc < 4; ++kc) {
#pragma unroll
        for (int ct = 0; ct < 4; ++ct) {
            short8 bfr = *(const short8*)(sWT + ((ch * 4 + ct) * 16 + l15) * 136 + quad * 8 + kc * 32);
            acc[ct] = __builtin_amdgcn_mfma_f32_16x16x32_bf16(afr[kc], bfr, acc[ct], 0, 0, 0);
        }
    }
    __syncthreads();   // all t reads done -> sU reusable

    // epilogue: msgT[col][edge] bf16, stride 66 (odd dword stride -> conflict-free)
#pragma unroll
    for (int ct = 0; ct < 4; ++ct) {
        int col = (ch * 4 + ct) * 16 + l15;
        uint2 pr;
        pr.x = pk_bf16(acc[ct][0], acc[ct][1]);
        pr.y = pk_bf16(acc[ct][2], acc[ct][3]);
        *(uint2*)(sU + col * 66 + rh * 16 + quad * 4) = pr;
    }
    __syncthreads();

    // phase 3: mask-driven segmented max, 4 threads/col (16 edges each).
    {
        int j = tid & 127;
        int q4 = tid >> 7;            // 0..3 (wave-uniform)
        int base = q4 * 16;
        const ushort* mrow = sU + j * 66 + base;
        float vals[16];
#pragma unroll
        for (int q = 0; q < 4; ++q) {
            ushort4 mv = *(const ushort4*)(mrow + q * 4);
            vals[q * 4 + 0] = bf2f(mv.x);
            vals[q * 4 + 1] = bf2f(mv.y);
            vals[q * 4 + 2] = bf2f(mv.z);
            vals[q * 4 + 3] = bf2f(mv.w);
        }
        unsigned mlo = __builtin_amdgcn_readfirstlane(sMask[0]);
        unsigned mhi = __builtin_amdgcn_readfirstlane(sMask[1]);
        unsigned b64 = __builtin_amdgcn_readfirstlane(sMask[2]);
        unsigned long long mask = ((unsigned long long)mhi << 32) | mlo;
        unsigned slice = (unsigned)((mask >> base) & 0xFFFFull);
        unsigned nextbit = (q4 == 3) ? (b64 & 1u) : (unsigned)((mask >> (base + 16)) & 1ull);
        unsigned ext = slice | (nextbit << 16);
        bool contFrom = !(ext & 1u);
        float run = 0.f;
        bool first = true;
#pragma unroll
        for (int e3 = 0; e3 < 16; ++e3) {
            float vv2 = vals[e3];
            bool hb = (ext >> e3) & 1u;
            run = (e3 == 0 || hb) ? vv2 : fmaxf(run, vv2);
            bool end = (e3 == 15) || ((ext >> (e3 + 1)) & 1u);
            if (end) {
                int d = sDst[base + e3];
                unsigned en = encf(run);
                unsigned* ap = agg + (size_t)d * HID + j;
                bool useAtomic = (first && contFrom) || ((e3 == 15) && !nextbit);
                if (useAtomic) atomicMax(ap, en);
                else *ap = en;
                first = false;
            }
        }
    }
}

// ---- pooling with fused layer-2 combine: x2 never materialized; 16 slices/graph ----
__global__ __launch_bounds__(256) void pool_kernel(const ushort* __restrict__ x1,
                                                   const unsigned* __restrict__ agg2,
                                                   const float* __restrict__ b2b,
                                                   const int* __restrict__ cnt2,
                                                   const int* __restrict__ batch,
                                                   float* __restrict__ pooled) {
    int g = blockIdx.x >> 4, s = blockIdx.x & 15;
    int tid = threadIdx.x;
    int lo = 0, hi = N_NODES;
    while (lo < hi) { int mid = (lo + hi) >> 1; if (batch[mid] < g) lo = mid + 1; else hi = mid; }
    int start = lo;
    hi = N_NODES;
    while (lo < hi) { int mid = (lo + hi) >> 1; if (batch[mid] < g + 1) lo = mid + 1; else hi = mid; }
    int end = lo;
    int cnt = end - start;
    int b0 = start + (int)((long long)cnt * s / 16);
    int b1 = start + (int)((long long)cnt * (s + 1) / 16);
    if (b1 <= b0) return;
    int j = tid & 127;
    bool isx2 = tid >= 128;
    float bbj = isx2 ? b2b[j] : 0.f;
    float mx = -INFINITY, sm = 0.f;
    for (int n = b0; n < b1; ++n) {
        float xv = bf2f(x1[(size_t)n * HID + j]);
        float vv;
        if (isx2) {
            float a = 0.f;
            if (cnt2[n] > 0) a = decf(agg2[(size_t)n * HID + j]) + bbj;
            vv = fmaxf(a + xv, 0.f);
        } else {
            vv = xv;
        }
        mx = fmaxf(mx, vv);
        sm += vv;
    }
    atomicMax((unsigned*)pooled + (size_t)g * 512 + tid, encf(mx));
    atomicAdd(pooled + (size_t)g * 512 + 256 + tid, sm);
}

// ---- final MLP + log_softmax ----
__global__ __launch_bounds__(128) void final_kernel(const float* __restrict__ pooled,
                                                    const int* __restrict__ batch,
                                                    const float* __restrict__ Wf1,
                                                    const float* __restrict__ bf1,
                                                    const float* __restrict__ Wf2,
                                                    const float* __restrict__ bf2,
                                                    float* __restrict__ out) {
    __shared__ float sP[512];
    __shared__ float sH[128];
    int g = blockIdx.x, tid = threadIdx.x;
    int lo = 0, hi = N_NODES;
    while (lo < hi) { int mid = (lo + hi) >> 1; if (batch[mid] < g) lo = mid + 1; else hi = mid; }
    int start = lo;
    hi = N_NODES;
    while (lo < hi) { int mid = (lo + hi) >> 1; if (batch[mid] < g + 1) lo = mid + 1; else hi = mid; }
    int cnt = lo - start;
    float inv = 1.f / (float)(cnt > 1 ? cnt : 1);
#pragma unroll
    for (int q = 0; q < 4; ++q) {
        int idx = q * 128 + tid;
        float raw;
        if (idx < 256) {
            unsigned e = ((const unsigned*)pooled)[(size_t)g * 512 + idx];
            raw = (e == 0u) ? 0.f : decf(e);
        } else {
            raw = pooled[(size_t)g * 512 + idx] * inv;
        }
        sP[idx] = raw;
    }
    __syncthreads();
    float acc = bf1[tid];
    for (int k = 0; k < 512; ++k) acc = fmaf(sP[k], Wf1[k * HID + tid], acc);
    sH[tid] = fmaxf(acc, 0.f);
    __syncthreads();
    if (tid < 2) {
        float l = bf2[tid];
        for (int k = 0; k < 128; ++k) l = fmaf(sH[k], Wf2[k * 2 + tid], l);
        sP[tid] = l;
    }
    __syncthreads();
    if (tid == 0) {
        float l0 = sP[0], l1 = sP[1];
        float m = fmaxf(l0, l1);
        float ls = m + logf(expf(l0 - m) + expf(l1 - m));
        out[g * 2 + 0] = l0 - ls;
        out[g * 2 + 1] = l1 - ls;
    }
}

extern "C" void kernel_launch(void* const* d_in, const int* in_sizes, int n_in,
                              void* d_out, int out_size, void* d_ws, size_t ws_size,
                              hipStream_t stream) {
    const float* x     = (const float*)d_in[0];
    const float* W_enc = (const float*)d_in[1];
    const float* b_enc = (const float*)d_in[2];
    const float* W0    = (const float*)d_in[3];
    const float* b0    = (const float*)d_in[4];
    const float* W1a   = (const float*)d_in[5];
    const float* b1a   = (const float*)d_in[6];
    const float* W1b   = (const float*)d_in[7];
    const float* b1b   = (const float*)d_in[8];
    const float* W2a   = (const float*)d_in[9];
    const float* b2a   = (const float*)d_in[10];
    const float* W2b   = (const float*)d_in[11];
    const float* b2b   = (const float*)d_in[12];
    const float* Wf1   = (const float*)d_in[13];
    const float* bf1   = (const float*)d_in[14];
    const float* Wf2   = (const float*)d_in[15];
    const float* bf2   = (const float*)d_in[16];
    const int* src1    = (const int*)d_in[17];
    const int* dst1    = (const int*)d_in[18];
    const int* src2    = (const int*)d_in[19];
    const int* dst2    = (const int*)d_in[20];
    const int* batch   = (const int*)d_in[21];

    const size_t NB = (size_t)N_NODES * HID;     // 12.8M elements
    ushort* hbuf  = (ushort*)d_ws;               // h -> x1 (in place, bf16)
    unsigned* agg1 = (unsigned*)(hbuf + NB);     // layer-1 segment-max (u32 encoded)
    unsigned* agg2 = agg1 + NB;                  // layer-2 segment-max
    ushort* ubuf  = (ushort*)(agg2 + NB);        // u bf16
    ushort* vbuf  = ubuf + NB;                   // v bf16
    ushort* WT    = vbuf + NB;                   // 6 x 16384 bf16: Wb1,Wb2,Wu1,Wv1,Wu2,Wv2
    ushort* WbT1 = WT;
    ushort* WbT2 = WT + 1 * HID * HID;
    ushort* WuT1 = WT + 2 * HID * HID;
    ushort* WvT1 = WT + 3 * HID * HID;
    ushort* WuT2 = WT + 4 * HID * HID;
    ushort* WvT2 = WT + 5 * HID * HID;
    float* wkey  = (float*)(WT + 6 * HID * HID);
    float* bias0 = wkey + 128;
    float* xkey  = bias0 + 128;                  // dense per-node key (N_NODES fp32)
    float* pooled = xkey + N_NODES;              // 128*512 fp32
    int* cnt    = (int*)(pooled + 128 * 512);    // 2*N_NODES (both layers)
    int* cursor = cnt + 2 * N_NODES;             // 2*N_NODES (scan1 local-exclusive)
    int* partials = cursor + 2 * N_NODES;        // 1024
    int* srcS = partials + 1024;                 // 2*N_EDGES sorted src
    int* dstS = srcS + 2 * N_EDGES;              // 2*N_EDGES sorted dst (dense expand)
    int* seq  = dstS + 2 * N_EDGES;              // 2*N_EDGES within-dst sequence

    const int edgeGrid = (N_EDGES + 63) / 64;         // 7813 windows of 64
    const int mmGrid   = (N_NODES + 127) / 128;       // 782
    const int prepGrid = 385 + SCAN1_B + 256;         // transpose+prep+zero(cnt,pooled)
    const int encHistGrid = BOTH_GRID + N_NODES / 2;  // hist + encode fused
    const int buildGrid = SCAN1_B + BOTH_GRID;        // expand/zbound + scatter-src

    transp_prep_kernel<<<prepGrid, 256, 0, stream>>>(W1b, W2b, W1a, W2a, W_enc, b_enc, W0, b0,
                                                     WT, wkey, bias0, cnt, pooled);
    encode_hist_kernel<<<encHistGrid, 256, 0, stream>>>(x, W0, wkey, bias0, hbuf, xkey,
                                                        dst1, dst2, cnt, seq);

    // ---- CSR finalize (atomic-free): scan + fused expand/zbound/scatter ----
    scan1_kernel<<<SCAN1_B, 256, 0, stream>>>(cnt, cursor, partials);
    scan2_kernel<<<1, 1024, 0, stream>>>(partials);
    build_kernel<<<buildGrid, 256, 0, stream>>>(src1, dst1, src2, dst2, cnt, cursor, partials,
                                                seq, srcS, dstS, agg1, agg2);

    // ---- layer 1 ----
    mm_mfma_dual_kernel<<<mmGrid, 512, 0, stream>>>(hbuf, nullptr, nullptr, nullptr, nullptr,
                                                    WuT1, WvT1, b1a, ubuf, vbuf, N_NODES);
    edge_kernel<<<edgeGrid, 512, 0, stream>>>(ubuf, vbuf, xkey, srcS, dstS, WbT1,
                                              W1a + 256 * HID, agg1);

    // ---- layer 2 (mm fuses layer-1 combine; writes x1 to hbuf) ----
    mm_mfma_dual_kernel<<<mmGrid, 512, 0, stream>>>(hbuf, agg1, cnt, b1b, hbuf,
                                                    WuT2, WvT2, b2a, ubuf, vbuf, N_NODES);
    edge_kernel<<<edgeGrid, 512, 0, stream>>>(ubuf, vbuf, xkey, srcS + N_EDGES, dstS + N_EDGES,
                                              WbT2, W2a + 256 * HID, agg2);

    // ---- pooling (layer-2 combine fused; pooled zeroed by transp_prep) + head ----
    pool_kernel<<<N_GRAPHS * 16, 256, 0, stream>>>(hbuf, agg2, b2b, cnt + N_NODES, batch, pooled);
    final_kernel<<<N_GRAPHS, 128, 0, stream>>>(pooled, batch, Wf1, bf1, Wf2, bf2, (float*)d_out);
}